// Round 7
// baseline (428.076 us; speedup 1.0000x reference)
//
#include <hip/hip_runtime.h>

typedef __attribute__((ext_vector_type(8)))  short  short8;
typedef __attribute__((ext_vector_type(4)))  float  float4v;
typedef __attribute__((ext_vector_type(16))) float  float16v;
typedef __attribute__((ext_vector_type(2)))  float  f32x2;

constexpr int HH = 256, WW = 256;
constexpr int PD = 258;                 // padded spatial dim (convs)
constexpr int PR = 260;                 // padded spatial dim (refg halo for deform)
constexpr size_t HWsz = (size_t)HH * WW;

__device__ inline unsigned short f2bf(float f) {
    unsigned int u = __builtin_bit_cast(unsigned int, f);
    u += 0x7FFFu + ((u >> 16) & 1u);
    return (unsigned short)(u >> 16);
}
__device__ inline float bfhalf(unsigned int w, int hi) {
    return __builtin_bit_cast(float, hi ? (w & 0xFFFF0000u) : (w << 16));
}
// unpack a uint holding 2 bf16 (lo=ch even, hi=ch odd) into packed f32 pair
__device__ inline f32x2 unpk2(unsigned int w) {
    f32x2 r;
    r.x = __builtin_bit_cast(float, w << 16);
    r.y = __builtin_bit_cast(float, w & 0xFFFF0000u);
    return r;
}
__device__ inline f32x2 splat2(float s) { f32x2 r; r.x = s; r.y = s; return r; }

// ---------------------------------------------------------------------------
// fp32 NCHW (64 ch) -> bf16 zero-padded NHWC [258][258][CDST], channels 0..63.
// If WRITE_G: also write group-major refg[b][g=cg][260][260][8ch] (halo-padded).
// ---------------------------------------------------------------------------
template<int CDST, bool WRITE_G>
__global__ __launch_bounds__(256) void nchw_to_nhwc(
    const float* __restrict__ src, unsigned short* __restrict__ dst,
    unsigned short* __restrict__ dst_g)
{
    const int px = threadIdx.x, h = blockIdx.x, bi = blockIdx.y;
    const float* s = src + (size_t)bi * 64 * HWsz + (size_t)h * WW + px;
    unsigned short* d = dst + (((size_t)bi * PD + (h + 1)) * PD + (px + 1)) * CDST;
#pragma unroll
    for (int cg = 0; cg < 8; ++cg) {
        float v[8];
#pragma unroll
        for (int j = 0; j < 8; ++j) v[j] = s[(size_t)(cg * 8 + j) * HWsz];
        uint4 pk;
        pk.x = f2bf(v[0]) | ((unsigned)f2bf(v[1]) << 16);
        pk.y = f2bf(v[2]) | ((unsigned)f2bf(v[3]) << 16);
        pk.z = f2bf(v[4]) | ((unsigned)f2bf(v[5]) << 16);
        pk.w = f2bf(v[6]) | ((unsigned)f2bf(v[7]) << 16);
        *(uint4*)&d[cg * 8] = pk;
        if (WRITE_G) {
            unsigned short* dg = dst_g +
                ((size_t)(bi * 8 + cg) * PR * PR + (size_t)(h + 1) * PR + (px + 1)) * 8;
            *(uint4*)dg = pk;
        }
    }
}

// ---------------------------------------------------------------------------
// Zero the 1-px borders of the three padded NHWC buffers (z=0..2) and the
// refg halo (z=3: rows {0,257,258} full width, cols {0,257,258} rows 1..256).
// ---------------------------------------------------------------------------
__global__ __launch_bounds__(256) void zero_border(
    unsigned short* __restrict__ p_off, unsigned short* __restrict__ p_cat,
    unsigned short* __restrict__ p_x1, unsigned short* __restrict__ refg)
{
    const int bi = blockIdx.y, which = blockIdx.z;
    if (which == 3) {
        const int total = 8 * 1548;   // 8 groups x (3*260 + 3*256) px
        for (int i = blockIdx.x * 256 + threadIdx.x; i < total; i += gridDim.x * 256) {
            int g = i / 1548, t = i - g * 1548;
            int r, c;
            if (t < 780)  { int rr = t / 260; c = t - rr * 260; r = rr == 0 ? 0 : 256 + rr; }
            else          { int u = t - 780; int cc = u >> 8; r = 1 + (u & 255); c = cc == 0 ? 0 : 256 + cc; }
            uint4 z = {0, 0, 0, 0};
            *(uint4*)&refg[((size_t)(bi * 8 + g) * PR * PR + (size_t)r * PR + c) * 8] = z;
        }
        return;
    }
    unsigned short* buf = which == 0 ? p_off : (which == 1 ? p_cat : p_x1);
    const int CIN = (which == 1) ? 128 : 64;
    const int NG = CIN / 8;
    unsigned short* p = buf + (size_t)bi * PD * PD * CIN;
    const int total = 1028 * 16;
    for (int i = blockIdx.x * 256 + threadIdx.x; i < total; i += gridDim.x * 256) {
        int g = i & 15;
        if (g >= NG) continue;
        int pxi = i >> 4;
        int r, c;
        if (pxi < 258)       { r = 0;   c = pxi; }
        else if (pxi < 516)  { r = 257; c = pxi - 258; }
        else if (pxi < 772)  { r = pxi - 516 + 1; c = 0; }
        else                 { r = pxi - 772 + 1; c = 257; }
        uint4 z = {0, 0, 0, 0};
        *(uint4*)&p[((size_t)r * PD + c) * CIN + g * 8] = z;
    }
}

// ---------------------------------------------------------------------------
// Fused weight packing, 32x32x16 A-frag order:
// wpk[((cot*KST + kstep)*64 + lane)*8 + j]
//   co = cot*32 + (lane&31); tap = kstep/(Cin/16);
//   ci = (kstep%(Cin/16))*16 + (lane>>5)*8 + j.  Zero-pad co >= Cout.
// ---------------------------------------------------------------------------
__device__ inline void pack_one(const float* __restrict__ w, short* __restrict__ wpk,
                                int Cout, int Cin, int e)
{
    int j = e & 7;
    int lane = (e >> 3) & 63;
    int ksp = 9 * (Cin / 16);
    int kstep = (e >> 9) % ksp;
    int cot = (e >> 9) / ksp;
    int tap = kstep / (Cin / 16);
    int ci = (kstep % (Cin / 16)) * 16 + (lane >> 5) * 8 + j;
    int co = cot * 32 + (lane & 31);
    float v = (co < Cout) ? w[((size_t)co * Cin + ci) * 9 + tap] : 0.f;
    wpk[e] = (short)f2bf(v);
}

__global__ __launch_bounds__(256) void pack_all(
    const float* __restrict__ w1, short* __restrict__ d1,    // 144,64 : 110592
    const float* __restrict__ w2, short* __restrict__ d2,    // 64,128 :  73728
    const float* __restrict__ w3, short* __restrict__ d3)    // 64,64  :  36864
{
    int e = blockIdx.x * 256 + threadIdx.x;
    if (e < 110592)               pack_one(w1, d1, 144, 64, e);
    else if (e < 110592 + 73728)  pack_one(w2, d2, 64, 128, e - 110592);
    else if (e < 221184)          pack_one(w3, d3, 64, 64,  e - 184320);
}

// ---------------------------------------------------------------------------
// Implicit-GEMM 3x3 conv, bf16 MFMA 32x32x16, barrier-free wave-private
// staging with T14 async-STAGE split: chunk ch+1's global loads are ISSUED
// before chunk ch's MFMA phase (latency hides under ~36 ksteps of MFMA) and
// WRITTEN to LDS after it.  st[5][3] is statically indexed (rule #20).
// MINW=3 (bounded VGPR -> 3 waves/SIMD).  Grid: (256 rows, B*COTB).
// MODE 0: dst_bf = NHWC [256][256][144], guard co<144 (deform offsets)
// MODE 1: dst_bf = padded NHWC [258][258][64], ReLU (x1)
// MODE 2: dst_f  = NCHW fp32, ReLU + bf16 residual from resid_bf (p_cat)
// ---------------------------------------------------------------------------
#define STAGE_LOAD(CH)                                                        \
    {                                                                         \
        _Pragma("unroll")                                                     \
        for (int t = 0; t < 5; ++t) {                                         \
            int i = t * 64 + lane;                                            \
            if (i < 264) {                                                    \
                int spx = i >> 2, so = i & 3;                                 \
                _Pragma("unroll")                                             \
                for (int r = 0; r < 3; ++r)                                   \
                    st[t][r] = *(const uint4*)(gband +                        \
                        ((size_t)r * PD + spx) * CIN + (CH) * 32 + so * 8);   \
            }                                                                 \
        }                                                                     \
    }

#define STAGE_WRITE()                                                         \
    {                                                                         \
        _Pragma("unroll")                                                     \
        for (int t = 0; t < 5; ++t) {                                         \
            int i = t * 64 + lane;                                            \
            if (i < 264) {                                                    \
                int spx = i >> 2, so = i & 3;                                 \
                _Pragma("unroll")                                             \
                for (int r = 0; r < 3; ++r)                                   \
                    *(uint4*)&my[(((size_t)r * 4 + so) * 66 + spx) * 8] = st[t][r]; \
            }                                                                 \
        }                                                                     \
    }

template<int CIN, int COF, int COTB, int MODE, int MINW>
__global__ __launch_bounds__(256, MINW) void conv_mfma_nb(
    const unsigned short* __restrict__ src,
    const short* __restrict__ wpk,
    const float* __restrict__ bias,
    unsigned short* __restrict__ dst_bf,
    float* __restrict__ dst_f,
    const unsigned short* __restrict__ resid_bf)
{
    constexpr int CHUNKS = CIN / 32;
    constexpr int KST = 9 * (CIN / 16);
    constexpr int WSEG = 3 * 4 * 66 * 8;     // shorts per wave = 12672 B

    __shared__ unsigned short lds[4 * WSEG]; // 50,688 B

    const int tid  = threadIdx.x;
    const int lane = tid & 63;
    const int wv   = tid >> 6;
    const int half = lane >> 5;
    const int n32  = lane & 31;
    const int h  = blockIdx.x;
    const int bi = blockIdx.y / COTB;
    const int cb = blockIdx.y % COTB;
    const int cbase = cb * COF * 32;

    unsigned short* my = lds + wv * WSEG;
    const unsigned short* srcB = src + (size_t)bi * PD * PD * CIN;
    const short8* wbase = (const short8*)wpk;
    const unsigned short* gband = srcB + ((size_t)h * PD + wv * 64) * CIN;

    float16v acc[COF][2];
#pragma unroll
    for (int f = 0; f < COF; ++f) {
        float16v bv;
#pragma unroll
        for (int reg = 0; reg < 16; ++reg) {
            int co = cbase + f * 32 + (reg >> 2) * 8 + 4 * half + (reg & 3);
            float b = 0.f;
            if (MODE != 0 || co < 144) b = bias[co];
            bv[reg] = b;
        }
        acc[f][0] = bv;
        acc[f][1] = bv;
    }

    uint4 st[5][3];

    // prologue: stage chunk 0
    STAGE_LOAD(0)
    STAGE_WRITE()

    for (int ch = 0; ch < CHUNKS; ++ch) {
        // issue next chunk's global loads BEFORE the MFMA phase (hidden)
        if (ch + 1 < CHUNKS) STAGE_LOAD(ch + 1)

        // ---- MFMA over 9 taps x 2 ci-16-steps (reads LDS, chunk ch) ----
#pragma unroll
        for (int tap = 0; tap < 9; ++tap) {
            const int row = tap / 3, dxo = tap % 3;
#pragma unroll
            for (int s = 0; s < 2; ++s) {
                const int kstep = tap * (CIN / 16) + ch * 2 + s;
                short8 a[COF];
#pragma unroll
                for (int f = 0; f < COF; ++f)
                    a[f] = wbase[((size_t)(cb * COF + f) * KST + kstep) * 64 + lane];
#pragma unroll
                for (int nt = 0; nt < 2; ++nt) {
                    short8 b = *(const short8*)
                        &my[(((size_t)row * 4 + s * 2 + half) * 66 + nt * 32 + dxo + n32) * 8];
#pragma unroll
                    for (int f = 0; f < COF; ++f)
                        acc[f][nt] = __builtin_amdgcn_mfma_f32_32x32x16_bf16(a[f], b, acc[f][nt], 0, 0, 0);
                }
            }
        }

        // write next chunk to LDS (same-wave DS ordering: safe after reads)
        if (ch + 1 < CHUNKS) STAGE_WRITE()
    }

    // epilogue: C layout col = n32 (px), row = (reg&3) + 8*(reg>>2) + 4*half
#pragma unroll
    for (int f = 0; f < COF; ++f) {
#pragma unroll
        for (int nt = 0; nt < 2; ++nt) {
            const int px = wv * 64 + nt * 32 + n32;
            float16v a = acc[f][nt];
#pragma unroll
            for (int q = 0; q < 4; ++q) {
                const int co4 = cbase + f * 32 + q * 8 + 4 * half;
                float v0 = a[q * 4 + 0], v1 = a[q * 4 + 1];
                float v2 = a[q * 4 + 2], v3 = a[q * 4 + 3];
                if (MODE == 0) {
                    if (co4 < 144) {
                        unsigned short* d = dst_bf + (size_t)bi * HWsz * 144;
                        uint2 pk;
                        pk.x = f2bf(v0) | ((unsigned)f2bf(v1) << 16);
                        pk.y = f2bf(v2) | ((unsigned)f2bf(v3) << 16);
                        *(uint2*)&d[((size_t)h * WW + px) * 144 + co4] = pk;
                    }
                } else if (MODE == 1) {
                    unsigned short* d = dst_bf + (size_t)bi * PD * PD * 64;
                    uint2 pk;
                    pk.x = f2bf(fmaxf(v0, 0.f)) | ((unsigned)f2bf(fmaxf(v1, 0.f)) << 16);
                    pk.y = f2bf(fmaxf(v2, 0.f)) | ((unsigned)f2bf(fmaxf(v3, 0.f)) << 16);
                    *(uint2*)&d[(((size_t)h + 1) * PD + (px + 1)) * 64 + co4] = pk;
                } else {
                    const unsigned short* rp = resid_bf + (size_t)bi * PD * PD * 128;
                    uint2 rv = *(const uint2*)&rp[(((size_t)h + 1) * PD + (px + 1)) * 128 + 64 + co4];
                    float r0 = bfhalf(rv.x, 0), r1 = bfhalf(rv.x, 1);
                    float r2 = bfhalf(rv.y, 0), r3 = bfhalf(rv.y, 1);
                    float* d = dst_f + (size_t)bi * 64 * HWsz + (size_t)h * WW + px;
                    d[(size_t)(co4 + 0) * HWsz] = fmaxf(v0, 0.f) + r0;
                    d[(size_t)(co4 + 1) * HWsz] = fmaxf(v1, 0.f) + r1;
                    d[(size_t)(co4 + 2) * HWsz] = fmaxf(v2, 0.f) + r2;
                    d[(size_t)(co4 + 3) * HWsz] = fmaxf(v3, 0.f) + r3;
                }
            }
        }
    }
}

// ---------------------------------------------------------------------------
// Deformable conv v7 (proven 63 us): packed-FP32 blend + einsum, zero-halo
// refg (260x260, clamp to [-1,256]), LDS-staged weights.
// ---------------------------------------------------------------------------
__global__ __launch_bounds__(256) void deform_k7(
    const unsigned short* __restrict__ refg,
    const unsigned short* __restrict__ doff,
    const float* __restrict__ wdef, const float* __restrict__ bdef,
    unsigned short* __restrict__ pcat_out)
{
    __shared__ float wsm2[576];    // [k][c][o]  (o pairs read as f32x2)
    const int L = blockIdx.x;
    const int xcd = L & 7;
    const int j = L >> 3;
    const int g = j & 7;
    const int r = (j >> 3) & 31;
    const int bi = j >> 8;
    const int h = xcd * 32 + r;
    const int px = threadIdx.x;

    for (int i = threadIdx.x; i < 576; i += 256) {
        int o = i & 7, c = (i >> 3) & 7, k = i >> 6;
        wsm2[i] = wdef[(size_t)g * 576 + o * 72 + c * 9 + k];
    }
    __syncthreads();

    const unsigned int* dp = (const unsigned int*)(
        doff + (((size_t)bi * HWsz) + (size_t)h * WW + px) * 144 + g * 18);
    unsigned int dw[9];
#pragma unroll
    for (int k = 0; k < 9; ++k) dw[k] = dp[k];

    f32x2 acc2[4];
#pragma unroll
    for (int o = 0; o < 4; ++o) {
        acc2[o].x = bdef[g * 8 + 2 * o];
        acc2[o].y = bdef[g * 8 + 2 * o + 1];
    }

    const unsigned short* rb = refg + (size_t)(bi * 8 + g) * PR * PR * 8;
    const float hf = (float)h, pxf = (float)px;

#pragma unroll
    for (int k = 0; k < 9; ++k) {
        float dy = bfhalf(dw[k], 0);
        float dx = bfhalf(dw[k], 1);
        // clamp to [-1, 256]: any sample outside lands entirely on the zero
        // halo with the interior-side weight forced to 0 -> exact semantics
        float py  = dy + (hf + (float)(k / 3 - 1));
        float pxs = dx + (pxf + (float)(k % 3 - 1));
        py  = fminf(fmaxf(py,  -1.f), 256.f);
        pxs = fminf(fmaxf(pxs, -1.f), 256.f);
        float fy = floorf(py), fx = floorf(pxs);
        float ly = py - fy, lx = pxs - fx;
        int y0 = (int)fy, x0 = (int)fx;
        int i00 = (y0 + 1) * PR + (x0 + 1);
        float omly = 1.f - ly, omlx = 1.f - lx;
        f32x2 w00 = splat2(omly * omlx), w01 = splat2(omly * lx);
        f32x2 w10 = splat2(ly * omlx),  w11 = splat2(ly * lx);

        const uint4 q00 = *(const uint4*)(rb + (size_t)i00 * 8);
        const uint4 q01 = *(const uint4*)(rb + (size_t)(i00 + 1) * 8);
        const uint4 q10 = *(const uint4*)(rb + (size_t)(i00 + PR) * 8);
        const uint4 q11 = *(const uint4*)(rb + (size_t)(i00 + PR + 1) * 8);
        union U { uint4 v; unsigned int a[4]; };
        U u00{q00}, u01{q01}, u10{q10}, u11{q11};

#pragma unroll
        for (int cw = 0; cw < 4; ++cw) {
            f32x2 sv = unpk2(u00.a[cw]) * w00;
            sv = __builtin_elementwise_fma(unpk2(u01.a[cw]), w01, sv);
            sv = __builtin_elementwise_fma(unpk2(u10.a[cw]), w10, sv);
            sv = __builtin_elementwise_fma(unpk2(u11.a[cw]), w11, sv);
            f32x2 bx = splat2(sv.x);
            f32x2 by = splat2(sv.y);
            const f32x2* wpa = (const f32x2*)&wsm2[((k * 8) + cw * 2) * 8];
            const f32x2* wpb = (const f32x2*)&wsm2[((k * 8) + cw * 2 + 1) * 8];
#pragma unroll
            for (int o = 0; o < 4; ++o) {
                acc2[o] = __builtin_elementwise_fma(wpa[o], bx, acc2[o]);
                acc2[o] = __builtin_elementwise_fma(wpb[o], by, acc2[o]);
            }
        }
    }

    unsigned short* po = pcat_out + (((size_t)bi * PD + (h + 1)) * PD + (px + 1)) * 128 + 64 + g * 8;
    uint4 pk;
    pk.x = f2bf(acc2[0].x) | ((unsigned)f2bf(acc2[0].y) << 16);
    pk.y = f2bf(acc2[1].x) | ((unsigned)f2bf(acc2[1].y) << 16);
    pk.z = f2bf(acc2[2].x) | ((unsigned)f2bf(acc2[2].y) << 16);
    pk.w = f2bf(acc2[3].x) | ((unsigned)f2bf(acc2[3].y) << 16);
    *(uint4*)po = pk;
}

// ---------------------------------------------------------------------------
extern "C" void kernel_launch(void* const* d_in, const int* in_sizes, int n_in,
                              void* d_out, int out_size, void* d_ws, size_t ws_size,
                              hipStream_t stream)
{
    const float* offset = (const float*)d_in[0];
    const float* ref    = (const float*)d_in[1];
    const float* w_off  = (const float*)d_in[2];
    const float* b_off  = (const float*)d_in[3];
    const float* w_def  = (const float*)d_in[4];
    const float* b_def  = (const float*)d_in[5];
    const float* w_r1   = (const float*)d_in[6];
    const float* b_r1   = (const float*)d_in[7];
    const float* w_r2   = (const float*)d_in[8];
    const float* b_r2   = (const float*)d_in[9];
    float* out = (float*)d_out;

    // workspace layout (ushort elems)
    unsigned short* p_off = (unsigned short*)d_ws;          // 2*258*258*64   = 8,520,192
    unsigned short* p_cat = p_off + (size_t)8520192;        // 2*258*258*128  = 17,040,384
    unsigned short* p_x1  = p_cat + (size_t)17040384;       // 8,520,192
    unsigned short* doff  = p_x1 + (size_t)8520192;         // 2*256*256*144  = 18,874,368
    unsigned short* refg  = doff + (size_t)18874368;        // 2*8*260*260*8  = 8,652,800
    short* wpk1  = (short*)(refg + (size_t)8652800);        // 110,592 (192co)
    short* wpkr1 = wpk1 + 110592;                           // 73,728
    short* wpkr2 = wpkr1 + 73728;                           // 36,864

    zero_border<<<dim3(65, 2, 4), 256, 0, stream>>>(p_off, p_cat, p_x1, refg);

    pack_all<<<dim3((221184 + 255) / 256), 256, 0, stream>>>(
        w_off, wpk1, w_r1, wpkr1, w_r2, wpkr2);

    nchw_to_nhwc<64, false><<<dim3(256, 2), 256, 0, stream>>>(offset, p_off, nullptr);
    nchw_to_nhwc<128, true><<<dim3(256, 2), 256, 0, stream>>>(ref, p_cat, refg);

    // conv1: 64 -> 144 (padded 192): COF=2 (64 co/block), COTB=3 (proven)
    conv_mfma_nb<64, 2, 3, 0, 3><<<dim3(256, 6), 256, 0, stream>>>(
        p_off, wpk1, b_off, doff, nullptr, nullptr);

    // deform (4096 linear blocks, XCD row-band swizzle)
    deform_k7<<<dim3(4096), 256, 0, stream>>>(refg, doff, w_def, b_def, p_cat);

    // r1: 128 -> 64, ReLU: COF=2, COTB=1
    conv_mfma_nb<128, 2, 1, 1, 3><<<dim3(256, 2), 256, 0, stream>>>(
        p_cat, wpkr1, b_r1, p_x1, nullptr, nullptr);

    // r2: 64 -> 64, ReLU + residual (bf16 from p_cat cols 64..127): COF=2
    conv_mfma_nb<64, 2, 1, 2, 3><<<dim3(256, 2), 256, 0, stream>>>(
        p_x1, wpkr2, b_r2, nullptr, out, p_cat);
}

// Round 8
// 377.655 us; speedup vs baseline: 1.1335x; 1.1335x over previous
//
#include <hip/hip_runtime.h>

typedef __attribute__((ext_vector_type(8)))  short  short8;
typedef __attribute__((ext_vector_type(4)))  float  float4v;
typedef __attribute__((ext_vector_type(16))) float  float16v;
typedef __attribute__((ext_vector_type(2)))  float  f32x2;

constexpr int HH = 256, WW = 256;
constexpr int PD = 258;                 // padded spatial dim (convs)
constexpr int PR = 260;                 // padded spatial dim (refg halo for deform)
constexpr size_t HWsz = (size_t)HH * WW;

__device__ inline unsigned short f2bf(float f) {
    unsigned int u = __builtin_bit_cast(unsigned int, f);
    u += 0x7FFFu + ((u >> 16) & 1u);
    return (unsigned short)(u >> 16);
}
__device__ inline float bfhalf(unsigned int w, int hi) {
    return __builtin_bit_cast(float, hi ? (w & 0xFFFF0000u) : (w << 16));
}
// unpack a uint holding 2 bf16 (lo=ch even, hi=ch odd) into packed f32 pair
__device__ inline f32x2 unpk2(unsigned int w) {
    f32x2 r;
    r.x = __builtin_bit_cast(float, w << 16);
    r.y = __builtin_bit_cast(float, w & 0xFFFF0000u);
    return r;
}
__device__ inline f32x2 splat2(float s) { f32x2 r; r.x = s; r.y = s; return r; }

// ---------------------------------------------------------------------------
// fp32 NCHW (64 ch) -> bf16 zero-padded NHWC [258][258][CDST], channels 0..63.
// If WRITE_G: also write group-major refg[b][g=cg][260][260][8ch] (halo-padded).
// ---------------------------------------------------------------------------
template<int CDST, bool WRITE_G>
__global__ __launch_bounds__(256) void nchw_to_nhwc(
    const float* __restrict__ src, unsigned short* __restrict__ dst,
    unsigned short* __restrict__ dst_g)
{
    const int px = threadIdx.x, h = blockIdx.x, bi = blockIdx.y;
    const float* s = src + (size_t)bi * 64 * HWsz + (size_t)h * WW + px;
    unsigned short* d = dst + (((size_t)bi * PD + (h + 1)) * PD + (px + 1)) * CDST;
#pragma unroll
    for (int cg = 0; cg < 8; ++cg) {
        float v[8];
#pragma unroll
        for (int j = 0; j < 8; ++j) v[j] = s[(size_t)(cg * 8 + j) * HWsz];
        uint4 pk;
        pk.x = f2bf(v[0]) | ((unsigned)f2bf(v[1]) << 16);
        pk.y = f2bf(v[2]) | ((unsigned)f2bf(v[3]) << 16);
        pk.z = f2bf(v[4]) | ((unsigned)f2bf(v[5]) << 16);
        pk.w = f2bf(v[6]) | ((unsigned)f2bf(v[7]) << 16);
        *(uint4*)&d[cg * 8] = pk;
        if (WRITE_G) {
            unsigned short* dg = dst_g +
                ((size_t)(bi * 8 + cg) * PR * PR + (size_t)(h + 1) * PR + (px + 1)) * 8;
            *(uint4*)dg = pk;
        }
    }
}

// ---------------------------------------------------------------------------
// Zero the 1-px borders of the three padded NHWC buffers (z=0..2) and the
// refg halo (z=3: rows {0,257,258} full width, cols {0,257,258} rows 1..256).
// ---------------------------------------------------------------------------
__global__ __launch_bounds__(256) void zero_border(
    unsigned short* __restrict__ p_off, unsigned short* __restrict__ p_cat,
    unsigned short* __restrict__ p_x1, unsigned short* __restrict__ refg)
{
    const int bi = blockIdx.y, which = blockIdx.z;
    if (which == 3) {
        const int total = 8 * 1548;   // 8 groups x (3*260 + 3*256) px
        for (int i = blockIdx.x * 256 + threadIdx.x; i < total; i += gridDim.x * 256) {
            int g = i / 1548, t = i - g * 1548;
            int r, c;
            if (t < 780)  { int rr = t / 260; c = t - rr * 260; r = rr == 0 ? 0 : 256 + rr; }
            else          { int u = t - 780; int cc = u >> 8; r = 1 + (u & 255); c = cc == 0 ? 0 : 256 + cc; }
            uint4 z = {0, 0, 0, 0};
            *(uint4*)&refg[((size_t)(bi * 8 + g) * PR * PR + (size_t)r * PR + c) * 8] = z;
        }
        return;
    }
    unsigned short* buf = which == 0 ? p_off : (which == 1 ? p_cat : p_x1);
    const int CIN = (which == 1) ? 128 : 64;
    const int NG = CIN / 8;
    unsigned short* p = buf + (size_t)bi * PD * PD * CIN;
    const int total = 1028 * 16;
    for (int i = blockIdx.x * 256 + threadIdx.x; i < total; i += gridDim.x * 256) {
        int g = i & 15;
        if (g >= NG) continue;
        int pxi = i >> 4;
        int r, c;
        if (pxi < 258)       { r = 0;   c = pxi; }
        else if (pxi < 516)  { r = 257; c = pxi - 258; }
        else if (pxi < 772)  { r = pxi - 516 + 1; c = 0; }
        else                 { r = pxi - 772 + 1; c = 257; }
        uint4 z = {0, 0, 0, 0};
        *(uint4*)&p[((size_t)r * PD + c) * CIN + g * 8] = z;
    }
}

// ---------------------------------------------------------------------------
// Fused weight packing, 32x32x16 A-frag order:
// wpk[((cot*KST + kstep)*64 + lane)*8 + j]
//   co = cot*32 + (lane&31); tap = kstep/(Cin/16);
//   ci = (kstep%(Cin/16))*16 + (lane>>5)*8 + j.  Zero-pad co >= Cout.
// ---------------------------------------------------------------------------
__device__ inline void pack_one(const float* __restrict__ w, short* __restrict__ wpk,
                                int Cout, int Cin, int e)
{
    int j = e & 7;
    int lane = (e >> 3) & 63;
    int ksp = 9 * (Cin / 16);
    int kstep = (e >> 9) % ksp;
    int cot = (e >> 9) / ksp;
    int tap = kstep / (Cin / 16);
    int ci = (kstep % (Cin / 16)) * 16 + (lane >> 5) * 8 + j;
    int co = cot * 32 + (lane & 31);
    float v = (co < Cout) ? w[((size_t)co * Cin + ci) * 9 + tap] : 0.f;
    wpk[e] = (short)f2bf(v);
}

__global__ __launch_bounds__(256) void pack_all(
    const float* __restrict__ w1, short* __restrict__ d1,    // 144,64 : 110592
    const float* __restrict__ w2, short* __restrict__ d2,    // 64,128 :  73728
    const float* __restrict__ w3, short* __restrict__ d3)    // 64,64  :  36864
{
    int e = blockIdx.x * 256 + threadIdx.x;
    if (e < 110592)               pack_one(w1, d1, 144, 64, e);
    else if (e < 110592 + 73728)  pack_one(w2, d2, 64, 128, e - 110592);
    else if (e < 221184)          pack_one(w3, d3, 64, 64,  e - 184320);
}

// ---------------------------------------------------------------------------
// Implicit-GEMM 3x3 conv, bf16 MFMA 32x32x16, barrier-free wave-private
// staging.  16-ci half-chunk staging (was 32-ci): LDS/wave 12672 -> 6336 B,
// so 25,344 B/block -> 6 blocks/CU (was 3, LDS-capped); MINW=4 caps VGPR at
// 128 -> 4 waves/SIMD (was 3).  Synchronous stage->MFMA per half-chunk (no
// register pipelining: three prior attempts all spilled to scratch).
// Grid: (256 rows, B*COTB).
// MODE 0: dst_bf = NHWC [256][256][144], guard co<144 (deform offsets)
// MODE 1: dst_bf = padded NHWC [258][258][64], ReLU (x1)
// MODE 2: dst_f  = NCHW fp32, ReLU + bf16 residual from resid_bf (p_cat)
// ---------------------------------------------------------------------------
template<int CIN, int COF, int COTB, int MODE, int MINW>
__global__ __launch_bounds__(256, MINW) void conv_mfma_nb(
    const unsigned short* __restrict__ src,
    const short* __restrict__ wpk,
    const float* __restrict__ bias,
    unsigned short* __restrict__ dst_bf,
    float* __restrict__ dst_f,
    const unsigned short* __restrict__ resid_bf)
{
    constexpr int STEPS = CIN / 16;          // 16-ci k-steps per tap
    constexpr int KST = 9 * STEPS;
    constexpr int WSEG = 3 * 2 * 66 * 8;     // shorts per wave = 6336 B

    __shared__ unsigned short lds[4 * WSEG]; // 25,344 B

    const int tid  = threadIdx.x;
    const int lane = tid & 63;
    const int wv   = tid >> 6;
    const int half = lane >> 5;
    const int n32  = lane & 31;
    const int h  = blockIdx.x;
    const int bi = blockIdx.y / COTB;
    const int cb = blockIdx.y % COTB;
    const int cbase = cb * COF * 32;

    unsigned short* my = lds + wv * WSEG;
    const unsigned short* srcB = src + (size_t)bi * PD * PD * CIN;
    const short8* wbase = (const short8*)wpk;

    float16v acc[COF][2];
#pragma unroll
    for (int f = 0; f < COF; ++f) {
        float16v bv;
#pragma unroll
        for (int reg = 0; reg < 16; ++reg) {
            int co = cbase + f * 32 + (reg >> 2) * 8 + 4 * half + (reg & 3);
            float b = 0.f;
            if (MODE != 0 || co < 144) b = bias[co];
            bv[reg] = b;
        }
        acc[f][0] = bv;
        acc[f][1] = bv;
    }

    for (int ch = 0; ch < STEPS; ++ch) {
        // ---- wave-private staging: 3 rows x 66 px x 16 ci (2 octets) ----
        const unsigned short* gband = srcB + ((size_t)h * PD + wv * 64) * CIN + ch * 16;
#pragma unroll
        for (int i0 = 0; i0 < 132; i0 += 64) {
            int i = i0 + lane;
            if (i0 + 64 > 132 && i >= 132) continue;
            int px = i >> 1, o = i & 1;
#pragma unroll
            for (int r = 0; r < 3; ++r) {
                uint4 v = *(const uint4*)(gband + ((size_t)r * PD + px) * CIN + o * 8);
                *(uint4*)&my[(((size_t)r * 2 + o) * 66 + px) * 8] = v;
            }
        }

        // ---- MFMA over 9 taps (one 16-ci kstep each) ----
#pragma unroll
        for (int tap = 0; tap < 9; ++tap) {
            const int row = tap / 3, dxo = tap % 3;
            const int kstep = tap * STEPS + ch;
            short8 a[COF];
#pragma unroll
            for (int f = 0; f < COF; ++f)
                a[f] = wbase[((size_t)(cb * COF + f) * KST + kstep) * 64 + lane];
#pragma unroll
            for (int nt = 0; nt < 2; ++nt) {
                short8 b = *(const short8*)
                    &my[(((size_t)row * 2 + half) * 66 + nt * 32 + dxo + n32) * 8];
#pragma unroll
                for (int f = 0; f < COF; ++f)
                    acc[f][nt] = __builtin_amdgcn_mfma_f32_32x32x16_bf16(a[f], b, acc[f][nt], 0, 0, 0);
            }
        }
    }

    // epilogue: C layout col = n32 (px), row = (reg&3) + 8*(reg>>2) + 4*half
#pragma unroll
    for (int f = 0; f < COF; ++f) {
#pragma unroll
        for (int nt = 0; nt < 2; ++nt) {
            const int px = wv * 64 + nt * 32 + n32;
            float16v a = acc[f][nt];
#pragma unroll
            for (int q = 0; q < 4; ++q) {
                const int co4 = cbase + f * 32 + q * 8 + 4 * half;
                float v0 = a[q * 4 + 0], v1 = a[q * 4 + 1];
                float v2 = a[q * 4 + 2], v3 = a[q * 4 + 3];
                if (MODE == 0) {
                    if (co4 < 144) {
                        unsigned short* d = dst_bf + (size_t)bi * HWsz * 144;
                        uint2 pk;
                        pk.x = f2bf(v0) | ((unsigned)f2bf(v1) << 16);
                        pk.y = f2bf(v2) | ((unsigned)f2bf(v3) << 16);
                        *(uint2*)&d[((size_t)h * WW + px) * 144 + co4] = pk;
                    }
                } else if (MODE == 1) {
                    unsigned short* d = dst_bf + (size_t)bi * PD * PD * 64;
                    uint2 pk;
                    pk.x = f2bf(fmaxf(v0, 0.f)) | ((unsigned)f2bf(fmaxf(v1, 0.f)) << 16);
                    pk.y = f2bf(fmaxf(v2, 0.f)) | ((unsigned)f2bf(fmaxf(v3, 0.f)) << 16);
                    *(uint2*)&d[(((size_t)h + 1) * PD + (px + 1)) * 64 + co4] = pk;
                } else {
                    const unsigned short* rp = resid_bf + (size_t)bi * PD * PD * 128;
                    uint2 rv = *(const uint2*)&rp[(((size_t)h + 1) * PD + (px + 1)) * 128 + 64 + co4];
                    float r0 = bfhalf(rv.x, 0), r1 = bfhalf(rv.x, 1);
                    float r2 = bfhalf(rv.y, 0), r3 = bfhalf(rv.y, 1);
                    float* d = dst_f + (size_t)bi * 64 * HWsz + (size_t)h * WW + px;
                    d[(size_t)(co4 + 0) * HWsz] = fmaxf(v0, 0.f) + r0;
                    d[(size_t)(co4 + 1) * HWsz] = fmaxf(v1, 0.f) + r1;
                    d[(size_t)(co4 + 2) * HWsz] = fmaxf(v2, 0.f) + r2;
                    d[(size_t)(co4 + 3) * HWsz] = fmaxf(v3, 0.f) + r3;
                }
            }
        }
    }
}

// ---------------------------------------------------------------------------
// Deformable conv v7 (proven 63 us): packed-FP32 blend + einsum, zero-halo
// refg (260x260, clamp to [-1,256]), LDS-staged weights.
// ---------------------------------------------------------------------------
__global__ __launch_bounds__(256) void deform_k7(
    const unsigned short* __restrict__ refg,
    const unsigned short* __restrict__ doff,
    const float* __restrict__ wdef, const float* __restrict__ bdef,
    unsigned short* __restrict__ pcat_out)
{
    __shared__ float wsm2[576];    // [k][c][o]  (o pairs read as f32x2)
    const int L = blockIdx.x;
    const int xcd = L & 7;
    const int j = L >> 3;
    const int g = j & 7;
    const int r = (j >> 3) & 31;
    const int bi = j >> 8;
    const int h = xcd * 32 + r;
    const int px = threadIdx.x;

    for (int i = threadIdx.x; i < 576; i += 256) {
        int o = i & 7, c = (i >> 3) & 7, k = i >> 6;
        wsm2[i] = wdef[(size_t)g * 576 + o * 72 + c * 9 + k];
    }
    __syncthreads();

    const unsigned int* dp = (const unsigned int*)(
        doff + (((size_t)bi * HWsz) + (size_t)h * WW + px) * 144 + g * 18);
    unsigned int dw[9];
#pragma unroll
    for (int k = 0; k < 9; ++k) dw[k] = dp[k];

    f32x2 acc2[4];
#pragma unroll
    for (int o = 0; o < 4; ++o) {
        acc2[o].x = bdef[g * 8 + 2 * o];
        acc2[o].y = bdef[g * 8 + 2 * o + 1];
    }

    const unsigned short* rb = refg + (size_t)(bi * 8 + g) * PR * PR * 8;
    const float hf = (float)h, pxf = (float)px;

#pragma unroll
    for (int k = 0; k < 9; ++k) {
        float dy = bfhalf(dw[k], 0);
        float dx = bfhalf(dw[k], 1);
        // clamp to [-1, 256]: any sample outside lands entirely on the zero
        // halo with the interior-side weight forced to 0 -> exact semantics
        float py  = dy + (hf + (float)(k / 3 - 1));
        float pxs = dx + (pxf + (float)(k % 3 - 1));
        py  = fminf(fmaxf(py,  -1.f), 256.f);
        pxs = fminf(fmaxf(pxs, -1.f), 256.f);
        float fy = floorf(py), fx = floorf(pxs);
        float ly = py - fy, lx = pxs - fx;
        int y0 = (int)fy, x0 = (int)fx;
        int i00 = (y0 + 1) * PR + (x0 + 1);
        float omly = 1.f - ly, omlx = 1.f - lx;
        f32x2 w00 = splat2(omly * omlx), w01 = splat2(omly * lx);
        f32x2 w10 = splat2(ly * omlx),  w11 = splat2(ly * lx);

        const uint4 q00 = *(const uint4*)(rb + (size_t)i00 * 8);
        const uint4 q01 = *(const uint4*)(rb + (size_t)(i00 + 1) * 8);
        const uint4 q10 = *(const uint4*)(rb + (size_t)(i00 + PR) * 8);
        const uint4 q11 = *(const uint4*)(rb + (size_t)(i00 + PR + 1) * 8);
        union U { uint4 v; unsigned int a[4]; };
        U u00{q00}, u01{q01}, u10{q10}, u11{q11};

#pragma unroll
        for (int cw = 0; cw < 4; ++cw) {
            f32x2 sv = unpk2(u00.a[cw]) * w00;
            sv = __builtin_elementwise_fma(unpk2(u01.a[cw]), w01, sv);
            sv = __builtin_elementwise_fma(unpk2(u10.a[cw]), w10, sv);
            sv = __builtin_elementwise_fma(unpk2(u11.a[cw]), w11, sv);
            f32x2 bx = splat2(sv.x);
            f32x2 by = splat2(sv.y);
            const f32x2* wpa = (const f32x2*)&wsm2[((k * 8) + cw * 2) * 8];
            const f32x2* wpb = (const f32x2*)&wsm2[((k * 8) + cw * 2 + 1) * 8];
#pragma unroll
            for (int o = 0; o < 4; ++o) {
                acc2[o] = __builtin_elementwise_fma(wpa[o], bx, acc2[o]);
                acc2[o] = __builtin_elementwise_fma(wpb[o], by, acc2[o]);
            }
        }
    }

    unsigned short* po = pcat_out + (((size_t)bi * PD + (h + 1)) * PD + (px + 1)) * 128 + 64 + g * 8;
    uint4 pk;
    pk.x = f2bf(acc2[0].x) | ((unsigned)f2bf(acc2[0].y) << 16);
    pk.y = f2bf(acc2[1].x) | ((unsigned)f2bf(acc2[1].y) << 16);
    pk.z = f2bf(acc2[2].x) | ((unsigned)f2bf(acc2[2].y) << 16);
    pk.w = f2bf(acc2[3].x) | ((unsigned)f2bf(acc2[3].y) << 16);
    *(uint4*)po = pk;
}

// ---------------------------------------------------------------------------
extern "C" void kernel_launch(void* const* d_in, const int* in_sizes, int n_in,
                              void* d_out, int out_size, void* d_ws, size_t ws_size,
                              hipStream_t stream)
{
    const float* offset = (const float*)d_in[0];
    const float* ref    = (const float*)d_in[1];
    const float* w_off  = (const float*)d_in[2];
    const float* b_off  = (const float*)d_in[3];
    const float* w_def  = (const float*)d_in[4];
    const float* b_def  = (const float*)d_in[5];
    const float* w_r1   = (const float*)d_in[6];
    const float* b_r1   = (const float*)d_in[7];
    const float* w_r2   = (const float*)d_in[8];
    const float* b_r2   = (const float*)d_in[9];
    float* out = (float*)d_out;

    // workspace layout (ushort elems)
    unsigned short* p_off = (unsigned short*)d_ws;          // 2*258*258*64   = 8,520,192
    unsigned short* p_cat = p_off + (size_t)8520192;        // 2*258*258*128  = 17,040,384
    unsigned short* p_x1  = p_cat + (size_t)17040384;       // 8,520,192
    unsigned short* doff  = p_x1 + (size_t)8520192;         // 2*256*256*144  = 18,874,368
    unsigned short* refg  = doff + (size_t)18874368;        // 2*8*260*260*8  = 8,652,800
    short* wpk1  = (short*)(refg + (size_t)8652800);        // 110,592 (192co)
    short* wpkr1 = wpk1 + 110592;                           // 73,728
    short* wpkr2 = wpkr1 + 73728;                           // 36,864

    zero_border<<<dim3(65, 2, 4), 256, 0, stream>>>(p_off, p_cat, p_x1, refg);

    pack_all<<<dim3((221184 + 255) / 256), 256, 0, stream>>>(
        w_off, wpk1, w_r1, wpkr1, w_r2, wpkr2);

    nchw_to_nhwc<64, false><<<dim3(256, 2), 256, 0, stream>>>(offset, p_off, nullptr);
    nchw_to_nhwc<128, true><<<dim3(256, 2), 256, 0, stream>>>(ref, p_cat, refg);

    // conv1: 64 -> 144 (padded 192): COF=2 (64 co/block), COTB=3
    conv_mfma_nb<64, 2, 3, 0, 4><<<dim3(256, 6), 256, 0, stream>>>(
        p_off, wpk1, b_off, doff, nullptr, nullptr);

    // deform (4096 linear blocks, XCD row-band swizzle)
    deform_k7<<<dim3(4096), 256, 0, stream>>>(refg, doff, w_def, b_def, p_cat);

    // r1: 128 -> 64, ReLU: COF=2, COTB=1
    conv_mfma_nb<128, 2, 1, 1, 4><<<dim3(256, 2), 256, 0, stream>>>(
        p_cat, wpkr1, b_r1, p_x1, nullptr, nullptr);

    // r2: 64 -> 64, ReLU + residual (bf16 from p_cat cols 64..127): COF=2
    conv_mfma_nb<64, 2, 1, 2, 4><<<dim3(256, 2), 256, 0, stream>>>(
        p_x1, wpkr2, b_r2, nullptr, out, p_cat);
}

// Round 9
// 330.997 us; speedup vs baseline: 1.2933x; 1.1410x over previous
//
#include <hip/hip_runtime.h>

typedef __attribute__((ext_vector_type(8)))  short  short8;
typedef __attribute__((ext_vector_type(4)))  float  float4v;
typedef __attribute__((ext_vector_type(16))) float  float16v;
typedef __attribute__((ext_vector_type(2)))  float  f32x2;

constexpr int HH = 256, WW = 256;
constexpr int PD = 258;                 // padded spatial dim (convs)
constexpr int PR = 260;                 // padded spatial dim (refg halo for deform)
constexpr size_t HWsz = (size_t)HH * WW;

__device__ inline unsigned short f2bf(float f) {
    unsigned int u = __builtin_bit_cast(unsigned int, f);
    u += 0x7FFFu + ((u >> 16) & 1u);
    return (unsigned short)(u >> 16);
}
__device__ inline float bfhalf(unsigned int w, int hi) {
    return __builtin_bit_cast(float, hi ? (w & 0xFFFF0000u) : (w << 16));
}
// unpack a uint holding 2 bf16 (lo=ch even, hi=ch odd) into packed f32 pair
__device__ inline f32x2 unpk2(unsigned int w) {
    f32x2 r;
    r.x = __builtin_bit_cast(float, w << 16);
    r.y = __builtin_bit_cast(float, w & 0xFFFF0000u);
    return r;
}
__device__ inline f32x2 splat2(float s) { f32x2 r; r.x = s; r.y = s; return r; }

// ---------------------------------------------------------------------------
// fp32 NCHW (64 ch) -> bf16 zero-padded NHWC [258][258][CDST], channels 0..63.
// If WRITE_G: also write group-major refg[b][g=cg][260][260][8ch] (halo-padded).
// ---------------------------------------------------------------------------
template<int CDST, bool WRITE_G>
__global__ __launch_bounds__(256) void nchw_to_nhwc(
    const float* __restrict__ src, unsigned short* __restrict__ dst,
    unsigned short* __restrict__ dst_g)
{
    const int px = threadIdx.x, h = blockIdx.x, bi = blockIdx.y;
    const float* s = src + (size_t)bi * 64 * HWsz + (size_t)h * WW + px;
    unsigned short* d = dst + (((size_t)bi * PD + (h + 1)) * PD + (px + 1)) * CDST;
#pragma unroll
    for (int cg = 0; cg < 8; ++cg) {
        float v[8];
#pragma unroll
        for (int j = 0; j < 8; ++j) v[j] = s[(size_t)(cg * 8 + j) * HWsz];
        uint4 pk;
        pk.x = f2bf(v[0]) | ((unsigned)f2bf(v[1]) << 16);
        pk.y = f2bf(v[2]) | ((unsigned)f2bf(v[3]) << 16);
        pk.z = f2bf(v[4]) | ((unsigned)f2bf(v[5]) << 16);
        pk.w = f2bf(v[6]) | ((unsigned)f2bf(v[7]) << 16);
        *(uint4*)&d[cg * 8] = pk;
        if (WRITE_G) {
            unsigned short* dg = dst_g +
                ((size_t)(bi * 8 + cg) * PR * PR + (size_t)(h + 1) * PR + (px + 1)) * 8;
            *(uint4*)dg = pk;
        }
    }
}

// ---------------------------------------------------------------------------
// Zero the 1-px borders of the three padded NHWC buffers (z=0..2) and the
// refg halo (z=3: rows {0,257,258} full width, cols {0,257,258} rows 1..256).
// ---------------------------------------------------------------------------
__global__ __launch_bounds__(256) void zero_border(
    unsigned short* __restrict__ p_off, unsigned short* __restrict__ p_cat,
    unsigned short* __restrict__ p_x1, unsigned short* __restrict__ refg)
{
    const int bi = blockIdx.y, which = blockIdx.z;
    if (which == 3) {
        const int total = 8 * 1548;   // 8 groups x (3*260 + 3*256) px
        for (int i = blockIdx.x * 256 + threadIdx.x; i < total; i += gridDim.x * 256) {
            int g = i / 1548, t = i - g * 1548;
            int r, c;
            if (t < 780)  { int rr = t / 260; c = t - rr * 260; r = rr == 0 ? 0 : 256 + rr; }
            else          { int u = t - 780; int cc = u >> 8; r = 1 + (u & 255); c = cc == 0 ? 0 : 256 + cc; }
            uint4 z = {0, 0, 0, 0};
            *(uint4*)&refg[((size_t)(bi * 8 + g) * PR * PR + (size_t)r * PR + c) * 8] = z;
        }
        return;
    }
    unsigned short* buf = which == 0 ? p_off : (which == 1 ? p_cat : p_x1);
    const int CIN = (which == 1) ? 128 : 64;
    const int NG = CIN / 8;
    unsigned short* p = buf + (size_t)bi * PD * PD * CIN;
    const int total = 1028 * 16;
    for (int i = blockIdx.x * 256 + threadIdx.x; i < total; i += gridDim.x * 256) {
        int g = i & 15;
        if (g >= NG) continue;
        int pxi = i >> 4;
        int r, c;
        if (pxi < 258)       { r = 0;   c = pxi; }
        else if (pxi < 516)  { r = 257; c = pxi - 258; }
        else if (pxi < 772)  { r = pxi - 516 + 1; c = 0; }
        else                 { r = pxi - 772 + 1; c = 257; }
        uint4 z = {0, 0, 0, 0};
        *(uint4*)&p[((size_t)r * PD + c) * CIN + g * 8] = z;
    }
}

// ---------------------------------------------------------------------------
// Fused weight packing, 32x32x16 A-frag order:
// wpk[((cot*KST + kstep)*64 + lane)*8 + j]
//   co = cot*32 + (lane&31); tap = kstep/(Cin/16);
//   ci = (kstep%(Cin/16))*16 + (lane>>5)*8 + j.  Zero-pad co >= Cout.
// ---------------------------------------------------------------------------
__device__ inline void pack_one(const float* __restrict__ w, short* __restrict__ wpk,
                                int Cout, int Cin, int e)
{
    int j = e & 7;
    int lane = (e >> 3) & 63;
    int ksp = 9 * (Cin / 16);
    int kstep = (e >> 9) % ksp;
    int cot = (e >> 9) / ksp;
    int tap = kstep / (Cin / 16);
    int ci = (kstep % (Cin / 16)) * 16 + (lane >> 5) * 8 + j;
    int co = cot * 32 + (lane & 31);
    float v = (co < Cout) ? w[((size_t)co * Cin + ci) * 9 + tap] : 0.f;
    wpk[e] = (short)f2bf(v);
}

__global__ __launch_bounds__(256) void pack_all(
    const float* __restrict__ w1, short* __restrict__ d1,    // 144,64 : 110592
    const float* __restrict__ w2, short* __restrict__ d2,    // 64,128 :  73728
    const float* __restrict__ w3, short* __restrict__ d3)    // 64,64  :  36864
{
    int e = blockIdx.x * 256 + threadIdx.x;
    if (e < 110592)               pack_one(w1, d1, 144, 64, e);
    else if (e < 110592 + 73728)  pack_one(w2, d2, 64, 128, e - 110592);
    else if (e < 221184)          pack_one(w3, d3, 64, 64,  e - 184320);
}

// ---------------------------------------------------------------------------
// Implicit-GEMM 3x3 conv, bf16 MFMA 32x32x16, barrier-free wave-private
// staging (R1 geometry: 32-ci chunks, MINW=3).  NEW: depth-2 software
// pipeline on the A-frag (weight) GLOBAL loads via a 3-slot ring (24 VGPR,
// all indices compile-time after full unroll).  Weights are L2-resident
// (~200 cyc); loading kstep t+2 while computing kstep t hides most of it.
// Grid: (256 rows, B*COTB).
// MODE 0: dst_bf = NHWC [256][256][144], guard co<144 (deform offsets)
// MODE 1: dst_bf = padded NHWC [258][258][64], ReLU (x1)
// MODE 2: dst_f  = NCHW fp32, ReLU + bf16 residual from resid_bf (p_cat)
// ---------------------------------------------------------------------------
template<int CIN, int COF, int COTB, int MODE, int MINW>
__global__ __launch_bounds__(256, MINW) void conv_mfma_nb(
    const unsigned short* __restrict__ src,
    const short* __restrict__ wpk,
    const float* __restrict__ bias,
    unsigned short* __restrict__ dst_bf,
    float* __restrict__ dst_f,
    const unsigned short* __restrict__ resid_bf)
{
    constexpr int CHUNKS = CIN / 32;
    constexpr int KST = 9 * (CIN / 16);
    constexpr int WSEG = 3 * 4 * 66 * 8;     // shorts per wave = 12672 B

    __shared__ unsigned short lds[4 * WSEG]; // 50,688 B

    const int tid  = threadIdx.x;
    const int lane = tid & 63;
    const int wv   = tid >> 6;
    const int half = lane >> 5;
    const int n32  = lane & 31;
    const int h  = blockIdx.x;
    const int bi = blockIdx.y / COTB;
    const int cb = blockIdx.y % COTB;
    const int cbase = cb * COF * 32;

    unsigned short* my = lds + wv * WSEG;
    const unsigned short* srcB = src + (size_t)bi * PD * PD * CIN;
    const short8* wbase = (const short8*)wpk;

    float16v acc[COF][2];
#pragma unroll
    for (int f = 0; f < COF; ++f) {
        float16v bv;
#pragma unroll
        for (int reg = 0; reg < 16; ++reg) {
            int co = cbase + f * 32 + (reg >> 2) * 8 + 4 * half + (reg & 3);
            float b = 0.f;
            if (MODE != 0 || co < 144) b = bias[co];
            bv[reg] = b;
        }
        acc[f][0] = bv;
        acc[f][1] = bv;
    }

    for (int ch = 0; ch < CHUNKS; ++ch) {
        // ---- wave-private staging: 3 rows x 66 px x 32 ci (4 octets) ----
        const unsigned short* gband = srcB + ((size_t)h * PD + wv * 64) * CIN + ch * 32;
#pragma unroll
        for (int i0 = 0; i0 < 264; i0 += 64) {
            int i = i0 + lane;
            if (i0 + 64 > 264 && i >= 264) continue;
            int px = i >> 2, o = i & 3;
#pragma unroll
            for (int r = 0; r < 3; ++r) {
                uint4 v = *(const uint4*)(gband + ((size_t)r * PD + px) * CIN + o * 8);
                *(uint4*)&my[(((size_t)r * 4 + o) * 66 + px) * 8] = v;
            }
        }

        // ---- MFMA over 18 ksteps (9 taps x 2 s), weight ring prefetch ----
        short8 abuf[3][COF];
#pragma unroll
        for (int p = 0; p < 2; ++p) {
            const int kp = (p >> 1) * (CIN / 16) + ch * 2 + (p & 1);
#pragma unroll
            for (int f = 0; f < COF; ++f)
                abuf[p][f] = wbase[((size_t)(cb * COF + f) * KST + kp) * 64 + lane];
        }
#pragma unroll
        for (int t = 0; t < 18; ++t) {
            const int tap = t >> 1, s = t & 1;
            const int row = tap / 3, dxo = tap % 3;
            if (t + 2 < 18) {
                const int t2 = t + 2;
                const int k2 = (t2 >> 1) * (CIN / 16) + ch * 2 + (t2 & 1);
#pragma unroll
                for (int f = 0; f < COF; ++f)
                    abuf[t2 % 3][f] = wbase[((size_t)(cb * COF + f) * KST + k2) * 64 + lane];
            }
#pragma unroll
            for (int nt = 0; nt < 2; ++nt) {
                short8 b = *(const short8*)
                    &my[(((size_t)row * 4 + s * 2 + half) * 66 + nt * 32 + dxo + n32) * 8];
#pragma unroll
                for (int f = 0; f < COF; ++f)
                    acc[f][nt] = __builtin_amdgcn_mfma_f32_32x32x16_bf16(abuf[t % 3][f], b, acc[f][nt], 0, 0, 0);
            }
        }
    }

    // epilogue: C layout col = n32 (px), row = (reg&3) + 8*(reg>>2) + 4*half
#pragma unroll
    for (int f = 0; f < COF; ++f) {
#pragma unroll
        for (int nt = 0; nt < 2; ++nt) {
            const int px = wv * 64 + nt * 32 + n32;
            float16v a = acc[f][nt];
#pragma unroll
            for (int q = 0; q < 4; ++q) {
                const int co4 = cbase + f * 32 + q * 8 + 4 * half;
                float v0 = a[q * 4 + 0], v1 = a[q * 4 + 1];
                float v2 = a[q * 4 + 2], v3 = a[q * 4 + 3];
                if (MODE == 0) {
                    if (co4 < 144) {
                        unsigned short* d = dst_bf + (size_t)bi * HWsz * 144;
                        uint2 pk;
                        pk.x = f2bf(v0) | ((unsigned)f2bf(v1) << 16);
                        pk.y = f2bf(v2) | ((unsigned)f2bf(v3) << 16);
                        *(uint2*)&d[((size_t)h * WW + px) * 144 + co4] = pk;
                    }
                } else if (MODE == 1) {
                    unsigned short* d = dst_bf + (size_t)bi * PD * PD * 64;
                    uint2 pk;
                    pk.x = f2bf(fmaxf(v0, 0.f)) | ((unsigned)f2bf(fmaxf(v1, 0.f)) << 16);
                    pk.y = f2bf(fmaxf(v2, 0.f)) | ((unsigned)f2bf(fmaxf(v3, 0.f)) << 16);
                    *(uint2*)&d[(((size_t)h + 1) * PD + (px + 1)) * 64 + co4] = pk;
                } else {
                    const unsigned short* rp = resid_bf + (size_t)bi * PD * PD * 128;
                    uint2 rv = *(const uint2*)&rp[(((size_t)h + 1) * PD + (px + 1)) * 128 + 64 + co4];
                    float r0 = bfhalf(rv.x, 0), r1 = bfhalf(rv.x, 1);
                    float r2 = bfhalf(rv.y, 0), r3 = bfhalf(rv.y, 1);
                    float* d = dst_f + (size_t)bi * 64 * HWsz + (size_t)h * WW + px;
                    d[(size_t)(co4 + 0) * HWsz] = fmaxf(v0, 0.f) + r0;
                    d[(size_t)(co4 + 1) * HWsz] = fmaxf(v1, 0.f) + r1;
                    d[(size_t)(co4 + 2) * HWsz] = fmaxf(v2, 0.f) + r2;
                    d[(size_t)(co4 + 3) * HWsz] = fmaxf(v3, 0.f) + r3;
                }
            }
        }
    }
}

// ---------------------------------------------------------------------------
// Deformable conv v7 (proven 63 us): packed-FP32 blend + einsum, zero-halo
// refg (260x260, clamp to [-1,256]), LDS-staged weights.
// ---------------------------------------------------------------------------
__global__ __launch_bounds__(256) void deform_k7(
    const unsigned short* __restrict__ refg,
    const unsigned short* __restrict__ doff,
    const float* __restrict__ wdef, const float* __restrict__ bdef,
    unsigned short* __restrict__ pcat_out)
{
    __shared__ float wsm2[576];    // [k][c][o]  (o pairs read as f32x2)
    const int L = blockIdx.x;
    const int xcd = L & 7;
    const int j = L >> 3;
    const int g = j & 7;
    const int r = (j >> 3) & 31;
    const int bi = j >> 8;
    const int h = xcd * 32 + r;
    const int px = threadIdx.x;

    for (int i = threadIdx.x; i < 576; i += 256) {
        int o = i & 7, c = (i >> 3) & 7, k = i >> 6;
        wsm2[i] = wdef[(size_t)g * 576 + o * 72 + c * 9 + k];
    }
    __syncthreads();

    const unsigned int* dp = (const unsigned int*)(
        doff + (((size_t)bi * HWsz) + (size_t)h * WW + px) * 144 + g * 18);
    unsigned int dw[9];
#pragma unroll
    for (int k = 0; k < 9; ++k) dw[k] = dp[k];

    f32x2 acc2[4];
#pragma unroll
    for (int o = 0; o < 4; ++o) {
        acc2[o].x = bdef[g * 8 + 2 * o];
        acc2[o].y = bdef[g * 8 + 2 * o + 1];
    }

    const unsigned short* rb = refg + (size_t)(bi * 8 + g) * PR * PR * 8;
    const float hf = (float)h, pxf = (float)px;

#pragma unroll
    for (int k = 0; k < 9; ++k) {
        float dy = bfhalf(dw[k], 0);
        float dx = bfhalf(dw[k], 1);
        // clamp to [-1, 256]: any sample outside lands entirely on the zero
        // halo with the interior-side weight forced to 0 -> exact semantics
        float py  = dy + (hf + (float)(k / 3 - 1));
        float pxs = dx + (pxf + (float)(k % 3 - 1));
        py  = fminf(fmaxf(py,  -1.f), 256.f);
        pxs = fminf(fmaxf(pxs, -1.f), 256.f);
        float fy = floorf(py), fx = floorf(pxs);
        float ly = py - fy, lx = pxs - fx;
        int y0 = (int)fy, x0 = (int)fx;
        int i00 = (y0 + 1) * PR + (x0 + 1);
        float omly = 1.f - ly, omlx = 1.f - lx;
        f32x2 w00 = splat2(omly * omlx), w01 = splat2(omly * lx);
        f32x2 w10 = splat2(ly * omlx),  w11 = splat2(ly * lx);

        const uint4 q00 = *(const uint4*)(rb + (size_t)i00 * 8);
        const uint4 q01 = *(const uint4*)(rb + (size_t)(i00 + 1) * 8);
        const uint4 q10 = *(const uint4*)(rb + (size_t)(i00 + PR) * 8);
        const uint4 q11 = *(const uint4*)(rb + (size_t)(i00 + PR + 1) * 8);
        union U { uint4 v; unsigned int a[4]; };
        U u00{q00}, u01{q01}, u10{q10}, u11{q11};

#pragma unroll
        for (int cw = 0; cw < 4; ++cw) {
            f32x2 sv = unpk2(u00.a[cw]) * w00;
            sv = __builtin_elementwise_fma(unpk2(u01.a[cw]), w01, sv);
            sv = __builtin_elementwise_fma(unpk2(u10.a[cw]), w10, sv);
            sv = __builtin_elementwise_fma(unpk2(u11.a[cw]), w11, sv);
            f32x2 bx = splat2(sv.x);
            f32x2 by = splat2(sv.y);
            const f32x2* wpa = (const f32x2*)&wsm2[((k * 8) + cw * 2) * 8];
            const f32x2* wpb = (const f32x2*)&wsm2[((k * 8) + cw * 2 + 1) * 8];
#pragma unroll
            for (int o = 0; o < 4; ++o) {
                acc2[o] = __builtin_elementwise_fma(wpa[o], bx, acc2[o]);
                acc2[o] = __builtin_elementwise_fma(wpb[o], by, acc2[o]);
            }
        }
    }

    unsigned short* po = pcat_out + (((size_t)bi * PD + (h + 1)) * PD + (px + 1)) * 128 + 64 + g * 8;
    uint4 pk;
    pk.x = f2bf(acc2[0].x) | ((unsigned)f2bf(acc2[0].y) << 16);
    pk.y = f2bf(acc2[1].x) | ((unsigned)f2bf(acc2[1].y) << 16);
    pk.z = f2bf(acc2[2].x) | ((unsigned)f2bf(acc2[2].y) << 16);
    pk.w = f2bf(acc2[3].x) | ((unsigned)f2bf(acc2[3].y) << 16);
    *(uint4*)po = pk;
}

// ---------------------------------------------------------------------------
extern "C" void kernel_launch(void* const* d_in, const int* in_sizes, int n_in,
                              void* d_out, int out_size, void* d_ws, size_t ws_size,
                              hipStream_t stream)
{
    const float* offset = (const float*)d_in[0];
    const float* ref    = (const float*)d_in[1];
    const float* w_off  = (const float*)d_in[2];
    const float* b_off  = (const float*)d_in[3];
    const float* w_def  = (const float*)d_in[4];
    const float* b_def  = (const float*)d_in[5];
    const float* w_r1   = (const float*)d_in[6];
    const float* b_r1   = (const float*)d_in[7];
    const float* w_r2   = (const float*)d_in[8];
    const float* b_r2   = (const float*)d_in[9];
    float* out = (float*)d_out;

    // workspace layout (ushort elems)
    unsigned short* p_off = (unsigned short*)d_ws;          // 2*258*258*64   = 8,520,192
    unsigned short* p_cat = p_off + (size_t)8520192;        // 2*258*258*128  = 17,040,384
    unsigned short* p_x1  = p_cat + (size_t)17040384;       // 8,520,192
    unsigned short* doff  = p_x1 + (size_t)8520192;         // 2*256*256*144  = 18,874,368
    unsigned short* refg  = doff + (size_t)18874368;        // 2*8*260*260*8  = 8,652,800
    short* wpk1  = (short*)(refg + (size_t)8652800);        // 110,592 (192co)
    short* wpkr1 = wpk1 + 110592;                           // 73,728
    short* wpkr2 = wpkr1 + 73728;                           // 36,864

    zero_border<<<dim3(65, 2, 4), 256, 0, stream>>>(p_off, p_cat, p_x1, refg);

    pack_all<<<dim3((221184 + 255) / 256), 256, 0, stream>>>(
        w_off, wpk1, w_r1, wpkr1, w_r2, wpkr2);

    nchw_to_nhwc<64, false><<<dim3(256, 2), 256, 0, stream>>>(offset, p_off, nullptr);
    nchw_to_nhwc<128, true><<<dim3(256, 2), 256, 0, stream>>>(ref, p_cat, refg);

    // conv1: 64 -> 144 (padded 192): COF=2 (64 co/block), COTB=3 (proven)
    conv_mfma_nb<64, 2, 3, 0, 3><<<dim3(256, 6), 256, 0, stream>>>(
        p_off, wpk1, b_off, doff, nullptr, nullptr);

    // deform (4096 linear blocks, XCD row-band swizzle)
    deform_k7<<<dim3(4096), 256, 0, stream>>>(refg, doff, w_def, b_def, p_cat);

    // r1: 128 -> 64, ReLU: COF=2, COTB=1
    conv_mfma_nb<128, 2, 1, 1, 3><<<dim3(256, 2), 256, 0, stream>>>(
        p_cat, wpkr1, b_r1, p_x1, nullptr, nullptr);

    // r2: 64 -> 64, ReLU + residual (bf16 from p_cat cols 64..127): COF=2
    conv_mfma_nb<64, 2, 1, 2, 3><<<dim3(256, 2), 256, 0, stream>>>(
        p_x1, wpkr2, b_r2, nullptr, out, p_cat);
}

// Round 10
// 326.759 us; speedup vs baseline: 1.3101x; 1.0130x over previous
//
#include <hip/hip_runtime.h>

typedef __attribute__((ext_vector_type(8)))  short  short8;
typedef __attribute__((ext_vector_type(4)))  float  float4v;
typedef __attribute__((ext_vector_type(16))) float  float16v;
typedef __attribute__((ext_vector_type(2)))  float  f32x2;

constexpr int HH = 256, WW = 256;
constexpr int PD = 258;                 // padded spatial dim (convs)
constexpr int PR = 260;                 // padded spatial dim (refg halo for deform)
constexpr size_t HWsz = (size_t)HH * WW;

__device__ inline unsigned short f2bf(float f) {
    unsigned int u = __builtin_bit_cast(unsigned int, f);
    u += 0x7FFFu + ((u >> 16) & 1u);
    return (unsigned short)(u >> 16);
}
__device__ inline float bfhalf(unsigned int w, int hi) {
    return __builtin_bit_cast(float, hi ? (w & 0xFFFF0000u) : (w << 16));
}
// unpack a uint holding 2 bf16 (lo=ch even, hi=ch odd) into packed f32 pair
__device__ inline f32x2 unpk2(unsigned int w) {
    f32x2 r;
    r.x = __builtin_bit_cast(float, w << 16);
    r.y = __builtin_bit_cast(float, w & 0xFFFF0000u);
    return r;
}
__device__ inline f32x2 splat2(float s) { f32x2 r; r.x = s; r.y = s; return r; }

// ---------------------------------------------------------------------------
// fp32 NCHW (64 ch) -> bf16 zero-padded NHWC [258][258][CDST], channels 0..63.
// If WRITE_G: also write group-major refg[b][g=cg][260][260][8ch] (halo-padded).
// ---------------------------------------------------------------------------
template<int CDST, bool WRITE_G>
__global__ __launch_bounds__(256) void nchw_to_nhwc(
    const float* __restrict__ src, unsigned short* __restrict__ dst,
    unsigned short* __restrict__ dst_g)
{
    const int px = threadIdx.x, h = blockIdx.x, bi = blockIdx.y;
    const float* s = src + (size_t)bi * 64 * HWsz + (size_t)h * WW + px;
    unsigned short* d = dst + (((size_t)bi * PD + (h + 1)) * PD + (px + 1)) * CDST;
#pragma unroll
    for (int cg = 0; cg < 8; ++cg) {
        float v[8];
#pragma unroll
        for (int j = 0; j < 8; ++j) v[j] = s[(size_t)(cg * 8 + j) * HWsz];
        uint4 pk;
        pk.x = f2bf(v[0]) | ((unsigned)f2bf(v[1]) << 16);
        pk.y = f2bf(v[2]) | ((unsigned)f2bf(v[3]) << 16);
        pk.z = f2bf(v[4]) | ((unsigned)f2bf(v[5]) << 16);
        pk.w = f2bf(v[6]) | ((unsigned)f2bf(v[7]) << 16);
        *(uint4*)&d[cg * 8] = pk;
        if (WRITE_G) {
            unsigned short* dg = dst_g +
                ((size_t)(bi * 8 + cg) * PR * PR + (size_t)(h + 1) * PR + (px + 1)) * 8;
            *(uint4*)dg = pk;
        }
    }
}

// ---------------------------------------------------------------------------
// Zero the 1-px borders of the three padded NHWC buffers (z=0..2) and the
// refg halo (z=3: rows {0,257,258} full width, cols {0,257,258} rows 1..256).
// ---------------------------------------------------------------------------
__global__ __launch_bounds__(256) void zero_border(
    unsigned short* __restrict__ p_off, unsigned short* __restrict__ p_cat,
    unsigned short* __restrict__ p_x1, unsigned short* __restrict__ refg)
{
    const int bi = blockIdx.y, which = blockIdx.z;
    if (which == 3) {
        const int total = 8 * 1548;   // 8 groups x (3*260 + 3*256) px
        for (int i = blockIdx.x * 256 + threadIdx.x; i < total; i += gridDim.x * 256) {
            int g = i / 1548, t = i - g * 1548;
            int r, c;
            if (t < 780)  { int rr = t / 260; c = t - rr * 260; r = rr == 0 ? 0 : 256 + rr; }
            else          { int u = t - 780; int cc = u >> 8; r = 1 + (u & 255); c = cc == 0 ? 0 : 256 + cc; }
            uint4 z = {0, 0, 0, 0};
            *(uint4*)&refg[((size_t)(bi * 8 + g) * PR * PR + (size_t)r * PR + c) * 8] = z;
        }
        return;
    }
    unsigned short* buf = which == 0 ? p_off : (which == 1 ? p_cat : p_x1);
    const int CIN = (which == 1) ? 128 : 64;
    const int NG = CIN / 8;
    unsigned short* p = buf + (size_t)bi * PD * PD * CIN;
    const int total = 1028 * 16;
    for (int i = blockIdx.x * 256 + threadIdx.x; i < total; i += gridDim.x * 256) {
        int g = i & 15;
        if (g >= NG) continue;
        int pxi = i >> 4;
        int r, c;
        if (pxi < 258)       { r = 0;   c = pxi; }
        else if (pxi < 516)  { r = 257; c = pxi - 258; }
        else if (pxi < 772)  { r = pxi - 516 + 1; c = 0; }
        else                 { r = pxi - 772 + 1; c = 257; }
        uint4 z = {0, 0, 0, 0};
        *(uint4*)&p[((size_t)r * PD + c) * CIN + g * 8] = z;
    }
}

// ---------------------------------------------------------------------------
// Fused weight packing, 32x32x16 A-frag order:
// wpk[((cot*KST + kstep)*64 + lane)*8 + j]
//   co = cot*32 + (lane&31); tap = kstep/(Cin/16);
//   ci = (kstep%(Cin/16))*16 + (lane>>5)*8 + j.  Zero-pad co >= Cout.
// ---------------------------------------------------------------------------
__device__ inline void pack_one(const float* __restrict__ w, short* __restrict__ wpk,
                                int Cout, int Cin, int e)
{
    int j = e & 7;
    int lane = (e >> 3) & 63;
    int ksp = 9 * (Cin / 16);
    int kstep = (e >> 9) % ksp;
    int cot = (e >> 9) / ksp;
    int tap = kstep / (Cin / 16);
    int ci = (kstep % (Cin / 16)) * 16 + (lane >> 5) * 8 + j;
    int co = cot * 32 + (lane & 31);
    float v = (co < Cout) ? w[((size_t)co * Cin + ci) * 9 + tap] : 0.f;
    wpk[e] = (short)f2bf(v);
}

__global__ __launch_bounds__(256) void pack_all(
    const float* __restrict__ w1, short* __restrict__ d1,    // 144,64 : 110592
    const float* __restrict__ w2, short* __restrict__ d2,    // 64,128 :  73728
    const float* __restrict__ w3, short* __restrict__ d3)    // 64,64  :  36864
{
    int e = blockIdx.x * 256 + threadIdx.x;
    if (e < 110592)               pack_one(w1, d1, 144, 64, e);
    else if (e < 110592 + 73728)  pack_one(w2, d2, 64, 128, e - 110592);
    else if (e < 221184)          pack_one(w3, d3, 64, 64,  e - 184320);
}

// ---------------------------------------------------------------------------
// Implicit-GEMM 3x3 conv, bf16 MFMA 32x32x16, barrier-free wave-private
// staging (R1 geometry: 32-ci chunks, MINW=3), with depth-2 weight-ring
// prefetch (R9: conv dispatches all dropped below deform).
// Grid: (256 rows, B*COTB).
// MODE 0: dst_bf = NHWC [256][256][144], guard co<144 (deform offsets)
// MODE 1: dst_bf = padded NHWC [258][258][64], ReLU (x1)
// MODE 2: dst_f  = NCHW fp32, ReLU + bf16 residual from resid_bf (p_cat)
// ---------------------------------------------------------------------------
template<int CIN, int COF, int COTB, int MODE, int MINW>
__global__ __launch_bounds__(256, MINW) void conv_mfma_nb(
    const unsigned short* __restrict__ src,
    const short* __restrict__ wpk,
    const float* __restrict__ bias,
    unsigned short* __restrict__ dst_bf,
    float* __restrict__ dst_f,
    const unsigned short* __restrict__ resid_bf)
{
    constexpr int CHUNKS = CIN / 32;
    constexpr int KST = 9 * (CIN / 16);
    constexpr int WSEG = 3 * 4 * 66 * 8;     // shorts per wave = 12672 B

    __shared__ unsigned short lds[4 * WSEG]; // 50,688 B

    const int tid  = threadIdx.x;
    const int lane = tid & 63;
    const int wv   = tid >> 6;
    const int half = lane >> 5;
    const int n32  = lane & 31;
    const int h  = blockIdx.x;
    const int bi = blockIdx.y / COTB;
    const int cb = blockIdx.y % COTB;
    const int cbase = cb * COF * 32;

    unsigned short* my = lds + wv * WSEG;
    const unsigned short* srcB = src + (size_t)bi * PD * PD * CIN;
    const short8* wbase = (const short8*)wpk;

    float16v acc[COF][2];
#pragma unroll
    for (int f = 0; f < COF; ++f) {
        float16v bv;
#pragma unroll
        for (int reg = 0; reg < 16; ++reg) {
            int co = cbase + f * 32 + (reg >> 2) * 8 + 4 * half + (reg & 3);
            float b = 0.f;
            if (MODE != 0 || co < 144) b = bias[co];
            bv[reg] = b;
        }
        acc[f][0] = bv;
        acc[f][1] = bv;
    }

    for (int ch = 0; ch < CHUNKS; ++ch) {
        // ---- wave-private staging: 3 rows x 66 px x 32 ci (4 octets) ----
        const unsigned short* gband = srcB + ((size_t)h * PD + wv * 64) * CIN + ch * 32;
#pragma unroll
        for (int i0 = 0; i0 < 264; i0 += 64) {
            int i = i0 + lane;
            if (i0 + 64 > 264 && i >= 264) continue;
            int px = i >> 2, o = i & 3;
#pragma unroll
            for (int r = 0; r < 3; ++r) {
                uint4 v = *(const uint4*)(gband + ((size_t)r * PD + px) * CIN + o * 8);
                *(uint4*)&my[(((size_t)r * 4 + o) * 66 + px) * 8] = v;
            }
        }

        // ---- MFMA over 18 ksteps (9 taps x 2 s), weight ring prefetch ----
        short8 abuf[3][COF];
#pragma unroll
        for (int p = 0; p < 2; ++p) {
            const int kp = (p >> 1) * (CIN / 16) + ch * 2 + (p & 1);
#pragma unroll
            for (int f = 0; f < COF; ++f)
                abuf[p][f] = wbase[((size_t)(cb * COF + f) * KST + kp) * 64 + lane];
        }
#pragma unroll
        for (int t = 0; t < 18; ++t) {
            const int tap = t >> 1, s = t & 1;
            const int row = tap / 3, dxo = tap % 3;
            if (t + 2 < 18) {
                const int t2 = t + 2;
                const int k2 = (t2 >> 1) * (CIN / 16) + ch * 2 + (t2 & 1);
#pragma unroll
                for (int f = 0; f < COF; ++f)
                    abuf[t2 % 3][f] = wbase[((size_t)(cb * COF + f) * KST + k2) * 64 + lane];
            }
#pragma unroll
            for (int nt = 0; nt < 2; ++nt) {
                short8 b = *(const short8*)
                    &my[(((size_t)row * 4 + s * 2 + half) * 66 + nt * 32 + dxo + n32) * 8];
#pragma unroll
                for (int f = 0; f < COF; ++f)
                    acc[f][nt] = __builtin_amdgcn_mfma_f32_32x32x16_bf16(abuf[t % 3][f], b, acc[f][nt], 0, 0, 0);
            }
        }
    }

    // epilogue: C layout col = n32 (px), row = (reg&3) + 8*(reg>>2) + 4*half
#pragma unroll
    for (int f = 0; f < COF; ++f) {
#pragma unroll
        for (int nt = 0; nt < 2; ++nt) {
            const int px = wv * 64 + nt * 32 + n32;
            float16v a = acc[f][nt];
#pragma unroll
            for (int q = 0; q < 4; ++q) {
                const int co4 = cbase + f * 32 + q * 8 + 4 * half;
                float v0 = a[q * 4 + 0], v1 = a[q * 4 + 1];
                float v2 = a[q * 4 + 2], v3 = a[q * 4 + 3];
                if (MODE == 0) {
                    if (co4 < 144) {
                        unsigned short* d = dst_bf + (size_t)bi * HWsz * 144;
                        uint2 pk;
                        pk.x = f2bf(v0) | ((unsigned)f2bf(v1) << 16);
                        pk.y = f2bf(v2) | ((unsigned)f2bf(v3) << 16);
                        *(uint2*)&d[((size_t)h * WW + px) * 144 + co4] = pk;
                    }
                } else if (MODE == 1) {
                    unsigned short* d = dst_bf + (size_t)bi * PD * PD * 64;
                    uint2 pk;
                    pk.x = f2bf(fmaxf(v0, 0.f)) | ((unsigned)f2bf(fmaxf(v1, 0.f)) << 16);
                    pk.y = f2bf(fmaxf(v2, 0.f)) | ((unsigned)f2bf(fmaxf(v3, 0.f)) << 16);
                    *(uint2*)&d[(((size_t)h + 1) * PD + (px + 1)) * 64 + co4] = pk;
                } else {
                    const unsigned short* rp = resid_bf + (size_t)bi * PD * PD * 128;
                    uint2 rv = *(const uint2*)&rp[(((size_t)h + 1) * PD + (px + 1)) * 128 + 64 + co4];
                    float r0 = bfhalf(rv.x, 0), r1 = bfhalf(rv.x, 1);
                    float r2 = bfhalf(rv.y, 0), r3 = bfhalf(rv.y, 1);
                    float* d = dst_f + (size_t)bi * 64 * HWsz + (size_t)h * WW + px;
                    d[(size_t)(co4 + 0) * HWsz] = fmaxf(v0, 0.f) + r0;
                    d[(size_t)(co4 + 1) * HWsz] = fmaxf(v1, 0.f) + r1;
                    d[(size_t)(co4 + 2) * HWsz] = fmaxf(v2, 0.f) + r2;
                    d[(size_t)(co4 + 3) * HWsz] = fmaxf(v3, 0.f) + r3;
                }
            }
        }
    }
}

// ---------------------------------------------------------------------------
// Deformable conv v10: k7's proven per-tap pattern, TWO ROWS per thread
// (h0, h0+1) interleaved in the same unrolled tap loop.  Two independent
// dependency chains -> gathers of one row overlap blend/einsum of the other.
// No cross-tap state (the k8/k9 failure mode); all locals scoped per tap,
// all arrays constant-indexed.  Grid: 2048 blocks.
// ---------------------------------------------------------------------------
#define DTAP(DWK, HF, ACC)                                                    \
    {                                                                         \
        float dy = bfhalf(DWK, 0);                                            \
        float dx = bfhalf(DWK, 1);                                            \
        float py  = dy + ((HF) + (float)(k / 3 - 1));                         \
        float pxs = dx + (pxf + (float)(k % 3 - 1));                          \
        py  = fminf(fmaxf(py,  -1.f), 256.f);                                 \
        pxs = fminf(fmaxf(pxs, -1.f), 256.f);                                 \
        float fy = floorf(py), fx = floorf(pxs);                              \
        float ly = py - fy, lx = pxs - fx;                                    \
        int i00 = ((int)fy + 1) * PR + ((int)fx + 1);                         \
        float omly = 1.f - ly, omlx = 1.f - lx;                               \
        f32x2 W00 = splat2(omly * omlx), W01 = splat2(omly * lx);             \
        f32x2 W10 = splat2(ly * omlx),  W11 = splat2(ly * lx);                \
        const uint4 q00 = *(const uint4*)(rb + (size_t)i00 * 8);              \
        const uint4 q01 = *(const uint4*)(rb + (size_t)(i00 + 1) * 8);        \
        const uint4 q10 = *(const uint4*)(rb + (size_t)(i00 + PR) * 8);       \
        const uint4 q11 = *(const uint4*)(rb + (size_t)(i00 + PR + 1) * 8);   \
        union U { uint4 v; unsigned int a[4]; };                              \
        U u00{q00}, u01{q01}, u10{q10}, u11{q11};                             \
        _Pragma("unroll")                                                     \
        for (int cw = 0; cw < 4; ++cw) {                                      \
            f32x2 sv = unpk2(u00.a[cw]) * W00;                                \
            sv = __builtin_elementwise_fma(unpk2(u01.a[cw]), W01, sv);        \
            sv = __builtin_elementwise_fma(unpk2(u10.a[cw]), W10, sv);        \
            sv = __builtin_elementwise_fma(unpk2(u11.a[cw]), W11, sv);        \
            f32x2 bx = splat2(sv.x);                                          \
            f32x2 by = splat2(sv.y);                                          \
            const f32x2* wpa = (const f32x2*)&wsm2[((k * 8) + cw * 2) * 8];   \
            const f32x2* wpb = (const f32x2*)&wsm2[((k * 8) + cw * 2 + 1) * 8];\
            _Pragma("unroll")                                                 \
            for (int o = 0; o < 4; ++o) {                                     \
                ACC[o] = __builtin_elementwise_fma(wpa[o], bx, ACC[o]);       \
                ACC[o] = __builtin_elementwise_fma(wpb[o], by, ACC[o]);       \
            }                                                                 \
        }                                                                     \
    }

__global__ __launch_bounds__(256) void deform_k10(
    const unsigned short* __restrict__ refg,
    const unsigned short* __restrict__ doff,
    const float* __restrict__ wdef, const float* __restrict__ bdef,
    unsigned short* __restrict__ pcat_out)
{
    __shared__ float wsm2[576];    // [k][c][o]  (o pairs read as f32x2)
    const int L = blockIdx.x;      // 2048 = 2 bi x 8 g x 16 row-pairs x 8 xcd
    const int xcd = L & 7;
    const int j = L >> 3;
    const int g = j & 7;
    const int r = (j >> 3) & 15;
    const int bi = j >> 7;
    const int h0 = xcd * 32 + r * 2;
    const int px = threadIdx.x;

    for (int i = threadIdx.x; i < 576; i += 256) {
        int o = i & 7, c = (i >> 3) & 7, k = i >> 6;
        wsm2[i] = wdef[(size_t)g * 576 + o * 72 + c * 9 + k];
    }
    __syncthreads();

    const unsigned int* dpA = (const unsigned int*)(
        doff + (((size_t)bi * HWsz) + (size_t)h0 * WW + px) * 144 + g * 18);
    const unsigned int* dpB = (const unsigned int*)(
        doff + (((size_t)bi * HWsz) + (size_t)(h0 + 1) * WW + px) * 144 + g * 18);
    unsigned int dwA[9], dwB[9];
#pragma unroll
    for (int k = 0; k < 9; ++k) dwA[k] = dpA[k];
#pragma unroll
    for (int k = 0; k < 9; ++k) dwB[k] = dpB[k];

    f32x2 accA[4], accB[4];
#pragma unroll
    for (int o = 0; o < 4; ++o) {
        accA[o].x = bdef[g * 8 + 2 * o];
        accA[o].y = bdef[g * 8 + 2 * o + 1];
        accB[o] = accA[o];
    }

    const unsigned short* rb = refg + (size_t)(bi * 8 + g) * PR * PR * 8;
    const float hfA = (float)h0, hfB = (float)(h0 + 1), pxf = (float)px;

#pragma unroll
    for (int k = 0; k < 9; ++k) {
        DTAP(dwA[k], hfA, accA)
        DTAP(dwB[k], hfB, accB)
    }

    unsigned short* poA = pcat_out + (((size_t)bi * PD + (h0 + 1)) * PD + (px + 1)) * 128 + 64 + g * 8;
    unsigned short* poB = pcat_out + (((size_t)bi * PD + (h0 + 2)) * PD + (px + 1)) * 128 + 64 + g * 8;
    uint4 pkA, pkB;
    pkA.x = f2bf(accA[0].x) | ((unsigned)f2bf(accA[0].y) << 16);
    pkA.y = f2bf(accA[1].x) | ((unsigned)f2bf(accA[1].y) << 16);
    pkA.z = f2bf(accA[2].x) | ((unsigned)f2bf(accA[2].y) << 16);
    pkA.w = f2bf(accA[3].x) | ((unsigned)f2bf(accA[3].y) << 16);
    pkB.x = f2bf(accB[0].x) | ((unsigned)f2bf(accB[0].y) << 16);
    pkB.y = f2bf(accB[1].x) | ((unsigned)f2bf(accB[1].y) << 16);
    pkB.z = f2bf(accB[2].x) | ((unsigned)f2bf(accB[2].y) << 16);
    pkB.w = f2bf(accB[3].x) | ((unsigned)f2bf(accB[3].y) << 16);
    *(uint4*)poA = pkA;
    *(uint4*)poB = pkB;
}

// ---------------------------------------------------------------------------
extern "C" void kernel_launch(void* const* d_in, const int* in_sizes, int n_in,
                              void* d_out, int out_size, void* d_ws, size_t ws_size,
                              hipStream_t stream)
{
    const float* offset = (const float*)d_in[0];
    const float* ref    = (const float*)d_in[1];
    const float* w_off  = (const float*)d_in[2];
    const float* b_off  = (const float*)d_in[3];
    const float* w_def  = (const float*)d_in[4];
    const float* b_def  = (const float*)d_in[5];
    const float* w_r1   = (const float*)d_in[6];
    const float* b_r1   = (const float*)d_in[7];
    const float* w_r2   = (const float*)d_in[8];
    const float* b_r2   = (const float*)d_in[9];
    float* out = (float*)d_out;

    // workspace layout (ushort elems)
    unsigned short* p_off = (unsigned short*)d_ws;          // 2*258*258*64   = 8,520,192
    unsigned short* p_cat = p_off + (size_t)8520192;        // 2*258*258*128  = 17,040,384
    unsigned short* p_x1  = p_cat + (size_t)17040384;       // 8,520,192
    unsigned short* doff  = p_x1 + (size_t)8520192;         // 2*256*256*144  = 18,874,368
    unsigned short* refg  = doff + (size_t)18874368;        // 2*8*260*260*8  = 8,652,800
    short* wpk1  = (short*)(refg + (size_t)8652800);        // 110,592 (192co)
    short* wpkr1 = wpk1 + 110592;                           // 73,728
    short* wpkr2 = wpkr1 + 73728;                           // 36,864

    zero_border<<<dim3(65, 2, 4), 256, 0, stream>>>(p_off, p_cat, p_x1, refg);

    pack_all<<<dim3((221184 + 255) / 256), 256, 0, stream>>>(
        w_off, wpk1, w_r1, wpkr1, w_r2, wpkr2);

    nchw_to_nhwc<64, false><<<dim3(256, 2), 256, 0, stream>>>(offset, p_off, nullptr);
    nchw_to_nhwc<128, true><<<dim3(256, 2), 256, 0, stream>>>(ref, p_cat, refg);

    // conv1: 64 -> 144 (padded 192): COF=2 (64 co/block), COTB=3 (proven)
    conv_mfma_nb<64, 2, 3, 0, 3><<<dim3(256, 6), 256, 0, stream>>>(
        p_off, wpk1, b_off, doff, nullptr, nullptr);

    // deform: 2 rows/thread ILP (2048 blocks, XCD row-band swizzle)
    deform_k10<<<dim3(2048), 256, 0, stream>>>(refg, doff, w_def, b_def, p_cat);

    // r1: 128 -> 64, ReLU: COF=2, COTB=1
    conv_mfma_nb<128, 2, 1, 1, 3><<<dim3(256, 2), 256, 0, stream>>>(
        p_cat, wpkr1, b_r1, p_x1, nullptr, nullptr);

    // r2: 64 -> 64, ReLU + residual (bf16 from p_cat cols 64..127): COF=2
    conv_mfma_nb<64, 2, 1, 2, 3><<<dim3(256, 2), 256, 0, stream>>>(
        p_x1, wpkr2, b_r2, nullptr, out, p_cat);
}

// Round 11
// 325.194 us; speedup vs baseline: 1.3164x; 1.0048x over previous
//
#include <hip/hip_runtime.h>

typedef __attribute__((ext_vector_type(8)))  short  short8;
typedef __attribute__((ext_vector_type(4)))  float  float4v;
typedef __attribute__((ext_vector_type(16))) float  float16v;
typedef __attribute__((ext_vector_type(2)))  float  f32x2;

constexpr int HH = 256, WW = 256;
constexpr int PD = 258;                 // padded spatial dim (convs)
constexpr int PR = 260;                 // padded spatial dim (refg halo for deform)
constexpr size_t HWsz = (size_t)HH * WW;

__device__ inline unsigned short f2bf(float f) {
    unsigned int u = __builtin_bit_cast(unsigned int, f);
    u += 0x7FFFu + ((u >> 16) & 1u);
    return (unsigned short)(u >> 16);
}
__device__ inline float bfhalf(unsigned int w, int hi) {
    return __builtin_bit_cast(float, hi ? (w & 0xFFFF0000u) : (w << 16));
}
// unpack a uint holding 2 bf16 (lo=ch even, hi=ch odd) into packed f32 pair
__device__ inline f32x2 unpk2(unsigned int w) {
    f32x2 r;
    r.x = __builtin_bit_cast(float, w << 16);
    r.y = __builtin_bit_cast(float, w & 0xFFFF0000u);
    return r;
}
__device__ inline f32x2 splat2(float s) { f32x2 r; r.x = s; r.y = s; return r; }

// ---------------------------------------------------------------------------
// fp32 NCHW (64 ch) -> bf16 zero-padded NHWC [258][258][CDST], channels 0..63.
// If WRITE_G: also write group-major refg[b][g=cg][260][260][8ch] (halo-padded).
// ---------------------------------------------------------------------------
template<int CDST, bool WRITE_G>
__global__ __launch_bounds__(256) void nchw_to_nhwc(
    const float* __restrict__ src, unsigned short* __restrict__ dst,
    unsigned short* __restrict__ dst_g)
{
    const int px = threadIdx.x, h = blockIdx.x, bi = blockIdx.y;
    const float* s = src + (size_t)bi * 64 * HWsz + (size_t)h * WW + px;
    unsigned short* d = dst + (((size_t)bi * PD + (h + 1)) * PD + (px + 1)) * CDST;
#pragma unroll
    for (int cg = 0; cg < 8; ++cg) {
        float v[8];
#pragma unroll
        for (int j = 0; j < 8; ++j) v[j] = s[(size_t)(cg * 8 + j) * HWsz];
        uint4 pk;
        pk.x = f2bf(v[0]) | ((unsigned)f2bf(v[1]) << 16);
        pk.y = f2bf(v[2]) | ((unsigned)f2bf(v[3]) << 16);
        pk.z = f2bf(v[4]) | ((unsigned)f2bf(v[5]) << 16);
        pk.w = f2bf(v[6]) | ((unsigned)f2bf(v[7]) << 16);
        *(uint4*)&d[cg * 8] = pk;
        if (WRITE_G) {
            unsigned short* dg = dst_g +
                ((size_t)(bi * 8 + cg) * PR * PR + (size_t)(h + 1) * PR + (px + 1)) * 8;
            *(uint4*)dg = pk;
        }
    }
}

// ---------------------------------------------------------------------------
// Zero the 1-px borders of the three padded NHWC buffers (z=0..2) and the
// refg halo (z=3: rows {0,257,258} full width, cols {0,257,258} rows 1..256).
// ---------------------------------------------------------------------------
__global__ __launch_bounds__(256) void zero_border(
    unsigned short* __restrict__ p_off, unsigned short* __restrict__ p_cat,
    unsigned short* __restrict__ p_x1, unsigned short* __restrict__ refg)
{
    const int bi = blockIdx.y, which = blockIdx.z;
    if (which == 3) {
        const int total = 8 * 1548;   // 8 groups x (3*260 + 3*256) px
        for (int i = blockIdx.x * 256 + threadIdx.x; i < total; i += gridDim.x * 256) {
            int g = i / 1548, t = i - g * 1548;
            int r, c;
            if (t < 780)  { int rr = t / 260; c = t - rr * 260; r = rr == 0 ? 0 : 256 + rr; }
            else          { int u = t - 780; int cc = u >> 8; r = 1 + (u & 255); c = cc == 0 ? 0 : 256 + cc; }
            uint4 z = {0, 0, 0, 0};
            *(uint4*)&refg[((size_t)(bi * 8 + g) * PR * PR + (size_t)r * PR + c) * 8] = z;
        }
        return;
    }
    unsigned short* buf = which == 0 ? p_off : (which == 1 ? p_cat : p_x1);
    const int CIN = (which == 1) ? 128 : 64;
    const int NG = CIN / 8;
    unsigned short* p = buf + (size_t)bi * PD * PD * CIN;
    const int total = 1028 * 16;
    for (int i = blockIdx.x * 256 + threadIdx.x; i < total; i += gridDim.x * 256) {
        int g = i & 15;
        if (g >= NG) continue;
        int pxi = i >> 4;
        int r, c;
        if (pxi < 258)       { r = 0;   c = pxi; }
        else if (pxi < 516)  { r = 257; c = pxi - 258; }
        else if (pxi < 772)  { r = pxi - 516 + 1; c = 0; }
        else                 { r = pxi - 772 + 1; c = 257; }
        uint4 z = {0, 0, 0, 0};
        *(uint4*)&p[((size_t)r * PD + c) * CIN + g * 8] = z;
    }
}

// ---------------------------------------------------------------------------
// Fused weight packing, 32x32x16 A-frag order:
// wpk[((cot*KST + kstep)*64 + lane)*8 + j]
//   co = cot*32 + (lane&31); tap = kstep/(Cin/16);
//   ci = (kstep%(Cin/16))*16 + (lane>>5)*8 + j.  Zero-pad co >= Cout.
// ---------------------------------------------------------------------------
__device__ inline void pack_one(const float* __restrict__ w, short* __restrict__ wpk,
                                int Cout, int Cin, int e)
{
    int j = e & 7;
    int lane = (e >> 3) & 63;
    int ksp = 9 * (Cin / 16);
    int kstep = (e >> 9) % ksp;
    int cot = (e >> 9) / ksp;
    int tap = kstep / (Cin / 16);
    int ci = (kstep % (Cin / 16)) * 16 + (lane >> 5) * 8 + j;
    int co = cot * 32 + (lane & 31);
    float v = (co < Cout) ? w[((size_t)co * Cin + ci) * 9 + tap] : 0.f;
    wpk[e] = (short)f2bf(v);
}

__global__ __launch_bounds__(256) void pack_all(
    const float* __restrict__ w1, short* __restrict__ d1,    // 144,64 : 110592
    const float* __restrict__ w2, short* __restrict__ d2,    // 64,128 :  73728
    const float* __restrict__ w3, short* __restrict__ d3)    // 64,64  :  36864
{
    int e = blockIdx.x * 256 + threadIdx.x;
    if (e < 110592)               pack_one(w1, d1, 144, 64, e);
    else if (e < 110592 + 73728)  pack_one(w2, d2, 64, 128, e - 110592);
    else if (e < 221184)          pack_one(w3, d3, 64, 64,  e - 184320);
}

// ---------------------------------------------------------------------------
// Implicit-GEMM 3x3 conv, bf16 MFMA 32x32x16, barrier-free wave-private
// staging (R1 geometry: 32-ci chunks, MINW=3), with depth-2 weight-ring
// prefetch (R9).  Grid: (256 rows, B*COTB).
// MODE 0: dst_bf = GROUP-PLANAR doff [bi][g][256][256][18] (deform offsets).
//         co4 -> (g = co4/18, c = co4%18); c==16 blocks straddle two group
//         records and split into two dword stores.
// MODE 1: dst_bf = padded NHWC [258][258][64], ReLU (x1)
// MODE 2: dst_f  = NCHW fp32, ReLU + bf16 residual from resid_bf (p_cat)
// ---------------------------------------------------------------------------
template<int CIN, int COF, int COTB, int MODE, int MINW>
__global__ __launch_bounds__(256, MINW) void conv_mfma_nb(
    const unsigned short* __restrict__ src,
    const short* __restrict__ wpk,
    const float* __restrict__ bias,
    unsigned short* __restrict__ dst_bf,
    float* __restrict__ dst_f,
    const unsigned short* __restrict__ resid_bf)
{
    constexpr int CHUNKS = CIN / 32;
    constexpr int KST = 9 * (CIN / 16);
    constexpr int WSEG = 3 * 4 * 66 * 8;     // shorts per wave = 12672 B

    __shared__ unsigned short lds[4 * WSEG]; // 50,688 B

    const int tid  = threadIdx.x;
    const int lane = tid & 63;
    const int wv   = tid >> 6;
    const int half = lane >> 5;
    const int n32  = lane & 31;
    const int h  = blockIdx.x;
    const int bi = blockIdx.y / COTB;
    const int cb = blockIdx.y % COTB;
    const int cbase = cb * COF * 32;

    unsigned short* my = lds + wv * WSEG;
    const unsigned short* srcB = src + (size_t)bi * PD * PD * CIN;
    const short8* wbase = (const short8*)wpk;

    float16v acc[COF][2];
#pragma unroll
    for (int f = 0; f < COF; ++f) {
        float16v bv;
#pragma unroll
        for (int reg = 0; reg < 16; ++reg) {
            int co = cbase + f * 32 + (reg >> 2) * 8 + 4 * half + (reg & 3);
            float b = 0.f;
            if (MODE != 0 || co < 144) b = bias[co];
            bv[reg] = b;
        }
        acc[f][0] = bv;
        acc[f][1] = bv;
    }

    for (int ch = 0; ch < CHUNKS; ++ch) {
        // ---- wave-private staging: 3 rows x 66 px x 32 ci (4 octets) ----
        const unsigned short* gband = srcB + ((size_t)h * PD + wv * 64) * CIN + ch * 32;
#pragma unroll
        for (int i0 = 0; i0 < 264; i0 += 64) {
            int i = i0 + lane;
            if (i0 + 64 > 264 && i >= 264) continue;
            int px = i >> 2, o = i & 3;
#pragma unroll
            for (int r = 0; r < 3; ++r) {
                uint4 v = *(const uint4*)(gband + ((size_t)r * PD + px) * CIN + o * 8);
                *(uint4*)&my[(((size_t)r * 4 + o) * 66 + px) * 8] = v;
            }
        }

        // ---- MFMA over 18 ksteps (9 taps x 2 s), weight ring prefetch ----
        short8 abuf[3][COF];
#pragma unroll
        for (int p = 0; p < 2; ++p) {
            const int kp = (p >> 1) * (CIN / 16) + ch * 2 + (p & 1);
#pragma unroll
            for (int f = 0; f < COF; ++f)
                abuf[p][f] = wbase[((size_t)(cb * COF + f) * KST + kp) * 64 + lane];
        }
#pragma unroll
        for (int t = 0; t < 18; ++t) {
            const int tap = t >> 1, s = t & 1;
            const int row = tap / 3, dxo = tap % 3;
            if (t + 2 < 18) {
                const int t2 = t + 2;
                const int k2 = (t2 >> 1) * (CIN / 16) + ch * 2 + (t2 & 1);
#pragma unroll
                for (int f = 0; f < COF; ++f)
                    abuf[t2 % 3][f] = wbase[((size_t)(cb * COF + f) * KST + k2) * 64 + lane];
            }
#pragma unroll
            for (int nt = 0; nt < 2; ++nt) {
                short8 b = *(const short8*)
                    &my[(((size_t)row * 4 + s * 2 + half) * 66 + nt * 32 + dxo + n32) * 8];
#pragma unroll
                for (int f = 0; f < COF; ++f)
                    acc[f][nt] = __builtin_amdgcn_mfma_f32_32x32x16_bf16(abuf[t % 3][f], b, acc[f][nt], 0, 0, 0);
            }
        }
    }

    // epilogue: C layout col = n32 (px), row = (reg&3) + 8*(reg>>2) + 4*half
#pragma unroll
    for (int f = 0; f < COF; ++f) {
#pragma unroll
        for (int nt = 0; nt < 2; ++nt) {
            const int px = wv * 64 + nt * 32 + n32;
            float16v a = acc[f][nt];
#pragma unroll
            for (int q = 0; q < 4; ++q) {
                const int co4 = cbase + f * 32 + q * 8 + 4 * half;
                float v0 = a[q * 4 + 0], v1 = a[q * 4 + 1];
                float v2 = a[q * 4 + 2], v3 = a[q * 4 + 3];
                if (MODE == 0) {
                    if (co4 < 144) {
                        // group-planar doff: [bi*8+g][h][px][18ch]
                        unsigned g = ((unsigned)co4 * 3641u) >> 16;   // co4/18
                        unsigned c = (unsigned)co4 - g * 18u;
                        unsigned lo = f2bf(v0) | ((unsigned)f2bf(v1) << 16);
                        unsigned hi = f2bf(v2) | ((unsigned)f2bf(v3) << 16);
                        unsigned short* rec = dst_bf +
                            (((size_t)(bi * 8 + g) * HWsz) + (size_t)h * WW + px) * 18;
                        if (c <= 14) {
                            *(unsigned*)&rec[c]     = lo;
                            *(unsigned*)&rec[c + 2] = hi;
                        } else {   // c == 16: ch16,17 here; ch18,19 -> group g+1 ch0,1
                            *(unsigned*)&rec[16] = lo;
                            unsigned short* rec2 = dst_bf +
                                (((size_t)(bi * 8 + g + 1) * HWsz) + (size_t)h * WW + px) * 18;
                            *(unsigned*)&rec2[0] = hi;
                        }
                    }
                } else if (MODE == 1) {
                    unsigned short* d = dst_bf + (size_t)bi * PD * PD * 64;
                    uint2 pk;
                    pk.x = f2bf(fmaxf(v0, 0.f)) | ((unsigned)f2bf(fmaxf(v1, 0.f)) << 16);
                    pk.y = f2bf(fmaxf(v2, 0.f)) | ((unsigned)f2bf(fmaxf(v3, 0.f)) << 16);
                    *(uint2*)&d[(((size_t)h + 1) * PD + (px + 1)) * 64 + co4] = pk;
                } else {
                    const unsigned short* rp = resid_bf + (size_t)bi * PD * PD * 128;
                    uint2 rv = *(const uint2*)&rp[(((size_t)h + 1) * PD + (px + 1)) * 128 + 64 + co4];
                    float r0 = bfhalf(rv.x, 0), r1 = bfhalf(rv.x, 1);
                    float r2 = bfhalf(rv.y, 0), r3 = bfhalf(rv.y, 1);
                    float* d = dst_f + (size_t)bi * 64 * HWsz + (size_t)h * WW + px;
                    d[(size_t)(co4 + 0) * HWsz] = fmaxf(v0, 0.f) + r0;
                    d[(size_t)(co4 + 1) * HWsz] = fmaxf(v1, 0.f) + r1;
                    d[(size_t)(co4 + 2) * HWsz] = fmaxf(v2, 0.f) + r2;
                    d[(size_t)(co4 + 3) * HWsz] = fmaxf(v3, 0.f) + r3;
                }
            }
        }
    }
}

// ---------------------------------------------------------------------------
// Deformable conv v11: k10's 2-row ILP + group-planar doff (36 B lane
// stride instead of 288 B -> ~4x fewer L1/L2 lines for the offset reads).
// Grid: 2048 blocks.
// ---------------------------------------------------------------------------
#define DTAP(DWK, HF, ACC)                                                    \
    {                                                                         \
        float dy = bfhalf(DWK, 0);                                            \
        float dx = bfhalf(DWK, 1);                                            \
        float py  = dy + ((HF) + (float)(k / 3 - 1));                         \
        float pxs = dx + (pxf + (float)(k % 3 - 1));                          \
        py  = fminf(fmaxf(py,  -1.f), 256.f);                                 \
        pxs = fminf(fmaxf(pxs, -1.f), 256.f);                                 \
        float fy = floorf(py), fx = floorf(pxs);                              \
        float ly = py - fy, lx = pxs - fx;                                    \
        int i00 = ((int)fy + 1) * PR + ((int)fx + 1);                         \
        float omly = 1.f - ly, omlx = 1.f - lx;                               \
        f32x2 W00 = splat2(omly * omlx), W01 = splat2(omly * lx);             \
        f32x2 W10 = splat2(ly * omlx),  W11 = splat2(ly * lx);                \
        const uint4 q00 = *(const uint4*)(rb + (size_t)i00 * 8);              \
        const uint4 q01 = *(const uint4*)(rb + (size_t)(i00 + 1) * 8);        \
        const uint4 q10 = *(const uint4*)(rb + (size_t)(i00 + PR) * 8);       \
        const uint4 q11 = *(const uint4*)(rb + (size_t)(i00 + PR + 1) * 8);   \
        union U { uint4 v; unsigned int a[4]; };                              \
        U u00{q00}, u01{q01}, u10{q10}, u11{q11};                             \
        _Pragma("unroll")                                                     \
        for (int cw = 0; cw < 4; ++cw) {                                      \
            f32x2 sv = unpk2(u00.a[cw]) * W00;                                \
            sv = __builtin_elementwise_fma(unpk2(u01.a[cw]), W01, sv);        \
            sv = __builtin_elementwise_fma(unpk2(u10.a[cw]), W10, sv);        \
            sv = __builtin_elementwise_fma(unpk2(u11.a[cw]), W11, sv);        \
            f32x2 bx = splat2(sv.x);                                          \
            f32x2 by = splat2(sv.y);                                          \
            const f32x2* wpa = (const f32x2*)&wsm2[((k * 8) + cw * 2) * 8];   \
            const f32x2* wpb = (const f32x2*)&wsm2[((k * 8) + cw * 2 + 1) * 8];\
            _Pragma("unroll")                                                 \
            for (int o = 0; o < 4; ++o) {                                     \
                ACC[o] = __builtin_elementwise_fma(wpa[o], bx, ACC[o]);       \
                ACC[o] = __builtin_elementwise_fma(wpb[o], by, ACC[o]);       \
            }                                                                 \
        }                                                                     \
    }

__global__ __launch_bounds__(256) void deform_k11(
    const unsigned short* __restrict__ refg,
    const unsigned short* __restrict__ doff,
    const float* __restrict__ wdef, const float* __restrict__ bdef,
    unsigned short* __restrict__ pcat_out)
{
    __shared__ float wsm2[576];    // [k][c][o]  (o pairs read as f32x2)
    const int L = blockIdx.x;      // 2048 = 2 bi x 8 g x 16 row-pairs x 8 xcd
    const int xcd = L & 7;
    const int j = L >> 3;
    const int g = j & 7;
    const int r = (j >> 3) & 15;
    const int bi = j >> 7;
    const int h0 = xcd * 32 + r * 2;
    const int px = threadIdx.x;

    for (int i = threadIdx.x; i < 576; i += 256) {
        int o = i & 7, c = (i >> 3) & 7, k = i >> 6;
        wsm2[i] = wdef[(size_t)g * 576 + o * 72 + c * 9 + k];
    }
    __syncthreads();

    // group-planar doff: record = 18 ushorts, lane stride 36 B
    const unsigned int* dpA = (const unsigned int*)(
        doff + (((size_t)(bi * 8 + g) * HWsz) + (size_t)h0 * WW + px) * 18);
    const unsigned int* dpB = (const unsigned int*)(
        doff + (((size_t)(bi * 8 + g) * HWsz) + (size_t)(h0 + 1) * WW + px) * 18);
    unsigned int dwA[9], dwB[9];
#pragma unroll
    for (int k = 0; k < 9; ++k) dwA[k] = dpA[k];
#pragma unroll
    for (int k = 0; k < 9; ++k) dwB[k] = dpB[k];

    f32x2 accA[4], accB[4];
#pragma unroll
    for (int o = 0; o < 4; ++o) {
        accA[o].x = bdef[g * 8 + 2 * o];
        accA[o].y = bdef[g * 8 + 2 * o + 1];
        accB[o] = accA[o];
    }

    const unsigned short* rb = refg + (size_t)(bi * 8 + g) * PR * PR * 8;
    const float hfA = (float)h0, hfB = (float)(h0 + 1), pxf = (float)px;

#pragma unroll
    for (int k = 0; k < 9; ++k) {
        DTAP(dwA[k], hfA, accA)
        DTAP(dwB[k], hfB, accB)
    }

    unsigned short* poA = pcat_out + (((size_t)bi * PD + (h0 + 1)) * PD + (px + 1)) * 128 + 64 + g * 8;
    unsigned short* poB = pcat_out + (((size_t)bi * PD + (h0 + 2)) * PD + (px + 1)) * 128 + 64 + g * 8;
    uint4 pkA, pkB;
    pkA.x = f2bf(accA[0].x) | ((unsigned)f2bf(accA[0].y) << 16);
    pkA.y = f2bf(accA[1].x) | ((unsigned)f2bf(accA[1].y) << 16);
    pkA.z = f2bf(accA[2].x) | ((unsigned)f2bf(accA[2].y) << 16);
    pkA.w = f2bf(accA[3].x) | ((unsigned)f2bf(accA[3].y) << 16);
    pkB.x = f2bf(accB[0].x) | ((unsigned)f2bf(accB[0].y) << 16);
    pkB.y = f2bf(accB[1].x) | ((unsigned)f2bf(accB[1].y) << 16);
    pkB.z = f2bf(accB[2].x) | ((unsigned)f2bf(accB[2].y) << 16);
    pkB.w = f2bf(accB[3].x) | ((unsigned)f2bf(accB[3].y) << 16);
    *(uint4*)poA = pkA;
    *(uint4*)poB = pkB;
}

// ---------------------------------------------------------------------------
extern "C" void kernel_launch(void* const* d_in, const int* in_sizes, int n_in,
                              void* d_out, int out_size, void* d_ws, size_t ws_size,
                              hipStream_t stream)
{
    const float* offset = (const float*)d_in[0];
    const float* ref    = (const float*)d_in[1];
    const float* w_off  = (const float*)d_in[2];
    const float* b_off  = (const float*)d_in[3];
    const float* w_def  = (const float*)d_in[4];
    const float* b_def  = (const float*)d_in[5];
    const float* w_r1   = (const float*)d_in[6];
    const float* b_r1   = (const float*)d_in[7];
    const float* w_r2   = (const float*)d_in[8];
    const float* b_r2   = (const float*)d_in[9];
    float* out = (float*)d_out;

    // workspace layout (ushort elems)
    unsigned short* p_off = (unsigned short*)d_ws;          // 2*258*258*64   = 8,520,192
    unsigned short* p_cat = p_off + (size_t)8520192;        // 2*258*258*128  = 17,040,384
    unsigned short* p_x1  = p_cat + (size_t)17040384;       // 8,520,192
    unsigned short* doff  = p_x1 + (size_t)8520192;         // 2*8*256*256*18 = 18,874,368 (group-planar)
    unsigned short* refg  = doff + (size_t)18874368;        // 2*8*260*260*8  = 8,652,800
    short* wpk1  = (short*)(refg + (size_t)8652800);        // 110,592 (192co)
    short* wpkr1 = wpk1 + 110592;                           // 73,728
    short* wpkr2 = wpkr1 + 73728;                           // 36,864

    zero_border<<<dim3(65, 2, 4), 256, 0, stream>>>(p_off, p_cat, p_x1, refg);

    pack_all<<<dim3((221184 + 255) / 256), 256, 0, stream>>>(
        w_off, wpk1, w_r1, wpkr1, w_r2, wpkr2);

    nchw_to_nhwc<64, false><<<dim3(256, 2), 256, 0, stream>>>(offset, p_off, nullptr);
    nchw_to_nhwc<128, true><<<dim3(256, 2), 256, 0, stream>>>(ref, p_cat, refg);

    // conv1: 64 -> 144 (padded 192): COF=2 (64 co/block), COTB=3 (proven)
    conv_mfma_nb<64, 2, 3, 0, 3><<<dim3(256, 6), 256, 0, stream>>>(
        p_off, wpk1, b_off, doff, nullptr, nullptr);

    // deform: 2 rows/thread ILP, group-planar doff reads (2048 blocks)
    deform_k11<<<dim3(2048), 256, 0, stream>>>(refg, doff, w_def, b_def, p_cat);

    // r1: 128 -> 64, ReLU: COF=2, COTB=1
    conv_mfma_nb<128, 2, 1, 1, 3><<<dim3(256, 2), 256, 0, stream>>>(
        p_cat, wpkr1, b_r1, p_x1, nullptr, nullptr);

    // r2: 64 -> 64, ReLU + residual (bf16 from p_cat cols 64..127): COF=2
    conv_mfma_nb<64, 2, 1, 2, 3><<<dim3(256, 2), 256, 0, stream>>>(
        p_x1, wpkr2, b_r2, nullptr, out, p_cat);
}